// Round 12
// baseline (632.763 us; speedup 1.0000x reference)
//
#include <hip/hip_runtime.h>
#include <hip/hip_bf16.h>
#include <math.h>

// Problem constants (CompactPointMamba: B=4, N=2048, E=128)
#define BATCH 4
#define NPTS  2048
#define L     4096      // 2*NPTS after concat of hilbert/trans orders
#define E     128
#define DI    256       // E*EXP
#define DS    16
#define DRR   8         // (E+15)//16
#define DCV   4
#define NBLK  2
#define NC    40
#define XDW   40        // DR + 2*DS
#define ROWS  (BATCH*L) // 16384
#define CH    16        // scan chunk length
#define NCH   256       // L / CH

typedef unsigned short u16;
typedef short short8 __attribute__((ext_vector_type(8)));
typedef float f32x4v __attribute__((ext_vector_type(4)));

// bf16 round-to-nearest-even helpers
__device__ __forceinline__ u16 f2bf(float x) {
  unsigned u = __float_as_uint(x);
  u = u + 0x7FFFu + ((u >> 16) & 1u);
  return (u16)(u >> 16);
}
__device__ __forceinline__ float bf2f(u16 h) {
  return __uint_as_float(((unsigned)h) << 16);
}
// fast softplus: ln(1+e^x) = ln2 * log2(1 + 2^(x*log2e))
__device__ __forceinline__ float softplusf(float x) {
  if (x > 20.f) return x;
  float t = __builtin_amdgcn_exp2f(x * 1.44269504f);
  return 0.69314718f * __builtin_amdgcn_logf(1.f + t);
}

// ---------------------------------------------------------------- embed + LN(block0) + split, row per wave
__global__ void embed_ln_split(const float* __restrict__ x,
                               const int* __restrict__ oh, const int* __restrict__ ot,
                               const float* __restrict__ pe_w, const float* __restrict__ pe_b,
                               const float* __restrict__ gamma, const float* __restrict__ beta,
                               const float* __restrict__ g, const float* __restrict__ bb,
                               float* __restrict__ h, u16* __restrict__ dhi, u16* __restrict__ dlo) {
  int wave = threadIdx.x >> 6;
  int lane = threadIdx.x & 63;
  int row = blockIdx.x * 4 + wave;        // b*L + n
  int n = row % L;
  int b = row / L;
  int gi = (n >= NPTS) ? 1 : 0;
  int nn = n - gi * NPTS;
  int src = gi ? ot[b * NPTS + nn] : oh[b * NPTS + nn];
  const float* xp = x + ((size_t)b * NPTS + src) * 3;
  float p0 = xp[0], p1 = xp[1], p2 = xp[2];
  int e0 = lane, e1 = lane + 64;
  float v0 = pe_b[e0] + p0 * pe_w[e0 * 3] + p1 * pe_w[e0 * 3 + 1] + p2 * pe_w[e0 * 3 + 2];
  float v1 = pe_b[e1] + p0 * pe_w[e1 * 3] + p1 * pe_w[e1 * 3 + 1] + p2 * pe_w[e1 * 3 + 2];
  v0 = v0 * gamma[gi * E + e0] + beta[gi * E + e0];
  v1 = v1 * gamma[gi * E + e1] + beta[gi * E + e1];
  size_t base = (size_t)row * E;
  h[base + e0] = v0;
  h[base + e1] = v1;
  // LN
  float s1 = v0 + v1, s2 = v0 * v0 + v1 * v1;
  #pragma unroll
  for (int off = 32; off > 0; off >>= 1) {
    s1 += __shfl_xor(s1, off);
    s2 += __shfl_xor(s2, off);
  }
  float m = s1 * (1.0f / E);
  float var = s2 * (1.0f / E) - m * m;
  float inv = rsqrtf(var + 1e-5f);
  float o0 = (v0 - m) * inv * g[e0] + bb[e0];
  float o1 = (v1 - m) * inv * g[e1] + bb[e1];
  u16 h0 = f2bf(o0), h1 = f2bf(o1);
  dhi[base + e0] = h0; dhi[base + e1] = h1;
  dlo[base + e0] = f2bf(o0 - bf2f(h0));
  dlo[base + e1] = f2bf(o1 - bf2f(h1));
}

// ---------------------------------------------------------------- split all weights (inproj + outw) in one dispatch
__global__ void split_all(const float* __restrict__ inproj, const float* __restrict__ outw,
                          u16* __restrict__ wihi, u16* __restrict__ wilo,
                          u16* __restrict__ wohi, u16* __restrict__ wolo) {
  const int n1 = NBLK * 2 * DI * E;
  const int n2 = NBLK * E * DI;
  int i = blockIdx.x * 256 + threadIdx.x;
  if (i < n1) {
    float v = inproj[i];
    u16 h = f2bf(v);
    wihi[i] = h; wilo[i] = f2bf(v - bf2f(h));
  } else if (i < n1 + n2) {
    int j = i - n1;
    float v = outw[j];
    u16 h = f2bf(v);
    wohi[j] = h; wolo[j] = f2bf(v - bf2f(h));
  }
}

// ---------------------------------------------------------------- layernorm -> bf16 hi/lo split (block 1)
__global__ void ln_split_kernel(const float* __restrict__ src, u16* __restrict__ dhi,
                                u16* __restrict__ dlo, const float* __restrict__ g,
                                const float* __restrict__ bb) {
  int wave = threadIdx.x >> 6;
  int lane = threadIdx.x & 63;
  int row = blockIdx.x * 4 + wave;
  const float* p = src + (size_t)row * E;
  float x0 = p[lane], x1 = p[lane + 64];
  float s1 = x0 + x1, s2 = x0 * x0 + x1 * x1;
  #pragma unroll
  for (int off = 32; off > 0; off >>= 1) {
    s1 += __shfl_xor(s1, off);
    s2 += __shfl_xor(s2, off);
  }
  float m = s1 * (1.0f / E);
  float v = s2 * (1.0f / E) - m * m;
  float inv = rsqrtf(v + 1e-5f);
  float v0 = (x0 - m) * inv * g[lane]      + bb[lane];
  float v1 = (x1 - m) * inv * g[lane + 64] + bb[lane + 64];
  size_t base = (size_t)row * E;
  u16 h0 = f2bf(v0), h1 = f2bf(v1);
  dhi[base + lane]      = h0;
  dhi[base + lane + 64] = h1;
  dlo[base + lane]      = f2bf(v0 - bf2f(h0));
  dlo[base + lane + 64] = f2bf(v1 - bf2f(h1));
}

// ---------------------------------------------------------------- LDS-staged split-bf16 MFMA GEMM
template<int BN, int ACC>
__global__ __launch_bounds__(256)
void mfma_gemm_lds(const u16* __restrict__ Ahi, const u16* __restrict__ Alo,
                   const u16* __restrict__ Bhi, const u16* __restrict__ Blo,
                   float* __restrict__ C, int M, int N, int K, int ldc) {
  constexpr int BM = 128, BK = 64, PITCH = 72;
  constexpr int MSUB = (BN == 128) ? 4 : 2;
  constexpr int NSUB = 4;
  __shared__ u16 sA[2][BM][PITCH];
  __shared__ u16 sB[2][BN][PITCH];
  int tid = threadIdx.x;
  int wave = tid >> 6, lane = tid & 63, quad = lane >> 4, l16 = lane & 15;
  int rowBase = blockIdx.x * BM, colBase = blockIdx.y * BN;
  int wrow = (BN == 128) ? (wave >> 1) * 64 : wave * 32;
  int wcol = (BN == 128) ? (wave & 1) * 64 : 0;
  f32x4v acc[MSUB][NSUB] = {};
  for (int k0 = 0; k0 < K; k0 += BK) {
    #pragma unroll
    for (int hl = 0; hl < 2; hl++) {
      const u16* srcA = hl ? Alo : Ahi;
      #pragma unroll
      for (int c = 0; c < BM * 8 / 256; c++) {
        int ch = c * 256 + tid;
        int row = ch >> 3, kc = ch & 7;
        float4 v = *(const float4*)(srcA + (size_t)(rowBase + row) * K + k0 + kc * 8);
        *(float4*)&sA[hl][row][kc * 8] = v;
      }
      const u16* srcB = hl ? Blo : Bhi;
      #pragma unroll
      for (int c = 0; c < BN * 8 / 256; c++) {
        int ch = c * 256 + tid;
        int row = ch >> 3, kc = ch & 7;
        float4 v = *(const float4*)(srcB + (size_t)(colBase + row) * K + k0 + kc * 8);
        *(float4*)&sB[hl][row][kc * 8] = v;
      }
    }
    __syncthreads();
    short8 afh[MSUB][2], afl[MSUB][2];
    #pragma unroll
    for (int i = 0; i < MSUB; i++)
      #pragma unroll
      for (int kf = 0; kf < 2; kf++) {
        afh[i][kf] = *(const short8*)&sA[0][wrow + i * 16 + l16][kf * 32 + quad * 8];
        afl[i][kf] = *(const short8*)&sA[1][wrow + i * 16 + l16][kf * 32 + quad * 8];
      }
    #pragma unroll
    for (int j = 0; j < NSUB; j++)
      #pragma unroll
      for (int kf = 0; kf < 2; kf++) {
        short8 bh = *(const short8*)&sB[0][wcol + j * 16 + l16][kf * 32 + quad * 8];
        short8 bl = *(const short8*)&sB[1][wcol + j * 16 + l16][kf * 32 + quad * 8];
        #pragma unroll
        for (int i = 0; i < MSUB; i++) {
          acc[i][j] = __builtin_amdgcn_mfma_f32_16x16x32_bf16(afh[i][kf], bh, acc[i][j], 0, 0, 0);
          acc[i][j] = __builtin_amdgcn_mfma_f32_16x16x32_bf16(afh[i][kf], bl, acc[i][j], 0, 0, 0);
          acc[i][j] = __builtin_amdgcn_mfma_f32_16x16x32_bf16(afl[i][kf], bh, acc[i][j], 0, 0, 0);
        }
      }
    __syncthreads();
  }
  int orow0 = rowBase + wrow + quad * 4;
  #pragma unroll
  for (int i = 0; i < MSUB; i++) {
    #pragma unroll
    for (int j = 0; j < NSUB; j++) {
      int cc = colBase + wcol + j * 16 + l16;
      #pragma unroll
      for (int r = 0; r < 4; r++) {
        size_t idx = (size_t)(orow0 + i * 16 + r) * ldc + cc;
        if (ACC) C[idx] += acc[i][j][r];
        else     C[idx] = acc[i][j][r];
      }
    }
  }
}

// ---------------------------------------------------------------- fused conv+silu+xproj+dtproj helper (in-LDS)
// Computes uc (conv+silu) per column d into regs + LDS, then xdbl[16][40] in LDS.
// uc_sh pitch DI+4 (rows offset 4 banks), xdbl_sh pitch 44.
__device__ __forceinline__ void conv_xproj_stage(
    const float* __restrict__ uz, const float* __restrict__ xw,
    const float* __restrict__ cw, const float* __restrict__ cb,
    int b, int c, int d, float (&ut)[CH],
    float (*uc_sh)[DI + 4], float (*xdbl_sh)[44]) {
  float w0 = cw[d * DCV], w1 = cw[d * DCV + 1], w2 = cw[d * DCV + 2], w3 = cw[d * DCV + 3];
  float cbv = cb[d];
  const float* up = uz + ((size_t)b * L + c * CH) * (2 * DI) + d;
  float p0 = 0.f, p1 = 0.f, p2 = 0.f;
  if (c > 0) {   // halo rows (t<0 only when c==0 -> zero pad)
    p0 = up[-3 * (2 * DI)];
    p1 = up[-2 * (2 * DI)];
    p2 = up[-1 * (2 * DI)];
  }
  #pragma unroll
  for (int t = 0; t < CH; t++) {
    float cur = up[t * (2 * DI)];
    float a = cbv + w0 * p0 + w1 * p1 + w2 * p2 + w3 * cur;
    float s = a / (1.f + __expf(-a));
    ut[t] = s;
    uc_sh[t][d] = s;
    p0 = p1; p1 = p2; p2 = cur;
  }
  __syncthreads();
  // xproj: thread (t = tid/16, og = tid%16) -> outputs og, og+16, og+32 (og<8)
  int t = threadIdx.x >> 4, og = threadIdx.x & 15;
  const float* ucrow = uc_sh[t];
  const float* x0 = xw + (size_t)og * DI;
  const float* x1 = xw + (size_t)(og + 16) * DI;
  const float* x2 = xw + (size_t)(og + 32) * DI;
  float a0 = 0.f, a1 = 0.f, a2 = 0.f;
  bool has2 = og < 8;
  #pragma unroll 8
  for (int k = 0; k < DI; k += 4) {
    float4 u4 = *(const float4*)&ucrow[k];
    float4 pa = *(const float4*)&x0[k];
    float4 pb = *(const float4*)&x1[k];
    a0 += u4.x * pa.x + u4.y * pa.y + u4.z * pa.z + u4.w * pa.w;
    a1 += u4.x * pb.x + u4.y * pb.y + u4.z * pb.z + u4.w * pb.w;
    if (has2) {
      float4 pc = *(const float4*)&x2[k];
      a2 += u4.x * pc.x + u4.y * pc.y + u4.z * pc.z + u4.w * pc.w;
    }
  }
  xdbl_sh[t][og] = a0;
  xdbl_sh[t][og + 16] = a1;
  if (has2) xdbl_sh[t][og + 32] = a2;
  __syncthreads();
}

// ---------------------------------------------------------------- scan pass A (conv+xproj+dtproj fused)
// hloc layout: [b][c][d][s]; sumd: [b][c][d]
__global__ __launch_bounds__(256, 4)
void scan_fusedA(const float* __restrict__ uz, const float* __restrict__ xw,
                 const float* __restrict__ cw, const float* __restrict__ cb,
                 const float* __restrict__ dtw, const float* __restrict__ dtb,
                 const float* __restrict__ A_log,
                 float* __restrict__ hloc, float* __restrict__ sumd) {
  int b = blockIdx.x / NCH, c = blockIdx.x % NCH;
  int d = threadIdx.x;
  __shared__ float uc_sh[CH][DI + 4];
  __shared__ float xdbl_sh[CH][44];
  float ut[CH];
  conv_xproj_stage(uz, xw, cw, cb, b, c, d, ut, uc_sh, xdbl_sh);
  float Av[DS];
  #pragma unroll
  for (int s = 0; s < DS; s++) Av[s] = -__expf(A_log[d * DS + s]);
  float4 q0 = *(const float4*)(dtw + d * DRR);
  float4 q1 = *(const float4*)(dtw + d * DRR + 4);
  float dbias = dtb[d];
  float dl[CH];
  float sd = 0.f;
  #pragma unroll
  for (int t = 0; t < CH; t++) {
    float4 D0 = *(const float4*)&xdbl_sh[t][0];
    float4 D1 = *(const float4*)&xdbl_sh[t][4];
    float v = dbias + D0.x * q0.x + D0.y * q0.y + D0.z * q0.z + D0.w * q0.w
                    + D1.x * q1.x + D1.y * q1.y + D1.z * q1.z + D1.w * q1.w;
    dl[t] = softplusf(v);
    sd += dl[t];
  }
  float st[DS] = {};
  #pragma unroll
  for (int t = 0; t < CH; t++) {
    float du = dl[t] * ut[t];
    float4 B0 = *(const float4*)&xdbl_sh[t][8];
    float4 B1 = *(const float4*)&xdbl_sh[t][12];
    float4 B2 = *(const float4*)&xdbl_sh[t][16];
    float4 B3 = *(const float4*)&xdbl_sh[t][20];
    float Bv[DS] = {B0.x, B0.y, B0.z, B0.w, B1.x, B1.y, B1.z, B1.w,
                    B2.x, B2.y, B2.z, B2.w, B3.x, B3.y, B3.z, B3.w};
    #pragma unroll
    for (int s = 0; s < DS; s++) {
      float a = __expf(dl[t] * Av[s]);
      st[s] = a * st[s] + du * Bv[s];
    }
  }
  size_t base = (((size_t)b * NCH + c) * DI + d) * DS;
  *(float4*)&hloc[base + 0]  = float4{st[0], st[1], st[2], st[3]};
  *(float4*)&hloc[base + 4]  = float4{st[4], st[5], st[6], st[7]};
  *(float4*)&hloc[base + 8]  = float4{st[8], st[9], st[10], st[11]};
  *(float4*)&hloc[base + 12] = float4{st[12], st[13], st[14], st[15]};
  sumd[((size_t)b * NCH + c) * DI + d] = sd;
}

// ---------------------------------------------------------------- scan pass B: coalesced serial scan, depth-8 prefetch
#define PB_G 8
__global__ __launch_bounds__(64)
void scan_passB(const float* __restrict__ A_log, const float* __restrict__ hloc,
                const float* __restrict__ sumd, float* __restrict__ hinit) {
  int tid = threadIdx.x;
  int dgroup = blockIdx.x % (DI / 4);
  int b = blockIdx.x / (DI / 4);
  int d = dgroup * 4 + (tid >> 4);
  int s = tid & 15;
  float Av = -__expf(A_log[d * DS + s]);
  size_t off = (size_t)b * NCH * DI * DS + dgroup * 64 + tid;
  size_t soff = (size_t)b * NCH * DI + d;
  const size_t HST = (size_t)DI * DS;
  float bv[PB_G], sd[PB_G], bvn[PB_G], sdn[PB_G];
  #pragma unroll
  for (int j = 0; j < PB_G; j++) {
    bv[j] = hloc[off + j * HST];
    sd[j] = sumd[soff + j * DI];
  }
  float X = 0.f;
  for (int g = 0; g < NCH / PB_G; g++) {
    if (g + 1 < NCH / PB_G) {
      #pragma unroll
      for (int j = 0; j < PB_G; j++) {
        bvn[j] = hloc[off + (j + PB_G) * HST];
        sdn[j] = sumd[soff + (j + PB_G) * DI];
      }
    }
    #pragma unroll
    for (int j = 0; j < PB_G; j++) {
      float a = __expf(Av * sd[j]);
      hinit[off + j * HST] = X;
      X = a * X + bv[j];
    }
    #pragma unroll
    for (int j = 0; j < PB_G; j++) { bv[j] = bvn[j]; sd[j] = sdn[j]; }
    off += PB_G * HST;
    soff += PB_G * DI;
  }
}

// ---------------------------------------------------------------- scan pass C (conv+xproj+dtproj fused; y -> bf16 hi/lo)
__global__ __launch_bounds__(256, 4)
void scan_fusedC(const float* __restrict__ uz, const float* __restrict__ xw,
                 const float* __restrict__ cw, const float* __restrict__ cb,
                 const float* __restrict__ dtw, const float* __restrict__ dtb,
                 const float* __restrict__ A_log, const float* __restrict__ Dp,
                 const float* __restrict__ hinit,
                 u16* __restrict__ yhi, u16* __restrict__ ylo) {
  int b = blockIdx.x / NCH, c = blockIdx.x % NCH;
  int d = threadIdx.x;
  __shared__ float uc_sh[CH][DI + 4];
  __shared__ float xdbl_sh[CH][44];
  float ut[CH];
  conv_xproj_stage(uz, xw, cw, cb, b, c, d, ut, uc_sh, xdbl_sh);
  float st[DS];
  size_t hbase = (((size_t)b * NCH + c) * DI + d) * DS;
  {
    float4 h0 = *(const float4*)&hinit[hbase + 0];
    float4 h1 = *(const float4*)&hinit[hbase + 4];
    float4 h2 = *(const float4*)&hinit[hbase + 8];
    float4 h3 = *(const float4*)&hinit[hbase + 12];
    st[0]=h0.x; st[1]=h0.y; st[2]=h0.z; st[3]=h0.w;
    st[4]=h1.x; st[5]=h1.y; st[6]=h1.z; st[7]=h1.w;
    st[8]=h2.x; st[9]=h2.y; st[10]=h2.z; st[11]=h2.w;
    st[12]=h3.x; st[13]=h3.y; st[14]=h3.z; st[15]=h3.w;
  }
  float Av[DS];
  #pragma unroll
  for (int s = 0; s < DS; s++) Av[s] = -__expf(A_log[d * DS + s]);
  float4 q0 = *(const float4*)(dtw + d * DRR);
  float4 q1 = *(const float4*)(dtw + d * DRR + 4);
  float dbias = dtb[d];
  float Dv = Dp[d];
  const float* z_p = uz + ((size_t)b * L + c * CH) * (2 * DI) + DI + d;
  size_t ybase = ((size_t)b * L + c * CH) * DI + d;
  float dl[CH];
  #pragma unroll
  for (int t = 0; t < CH; t++) {
    float4 D0 = *(const float4*)&xdbl_sh[t][0];
    float4 D1 = *(const float4*)&xdbl_sh[t][4];
    float v = dbias + D0.x * q0.x + D0.y * q0.y + D0.z * q0.z + D0.w * q0.w
                    + D1.x * q1.x + D1.y * q1.y + D1.z * q1.z + D1.w * q1.w;
    dl[t] = softplusf(v);
  }
  float znext = z_p[0];
  #pragma unroll
  for (int t = 0; t < CH; t++) {
    float zz = znext;
    if (t < CH - 1) znext = z_p[(size_t)(t + 1) * (2 * DI)];
    float du = dl[t] * ut[t];
    float acc = Dv * ut[t];
    float4 B0 = *(const float4*)&xdbl_sh[t][8];
    float4 B1 = *(const float4*)&xdbl_sh[t][12];
    float4 B2 = *(const float4*)&xdbl_sh[t][16];
    float4 B3 = *(const float4*)&xdbl_sh[t][20];
    float4 C0 = *(const float4*)&xdbl_sh[t][24];
    float4 C1 = *(const float4*)&xdbl_sh[t][28];
    float4 C2 = *(const float4*)&xdbl_sh[t][32];
    float4 C3 = *(const float4*)&xdbl_sh[t][36];
    float Bv[DS] = {B0.x, B0.y, B0.z, B0.w, B1.x, B1.y, B1.z, B1.w,
                    B2.x, B2.y, B2.z, B2.w, B3.x, B3.y, B3.z, B3.w};
    float Cv[DS] = {C0.x, C0.y, C0.z, C0.w, C1.x, C1.y, C1.z, C1.w,
                    C2.x, C2.y, C2.z, C2.w, C3.x, C3.y, C3.z, C3.w};
    #pragma unroll
    for (int s = 0; s < DS; s++) {
      float a = __expf(dl[t] * Av[s]);
      st[s] = a * st[s] + du * Bv[s];
      acc += st[s] * Cv[s];
    }
    float v = acc * (zz / (1.f + __expf(-zz)));
    u16 hh = f2bf(v);
    yhi[ybase + (size_t)t * DI] = hh;
    ylo[ybase + (size_t)t * DI] = f2bf(v - bf2f(hh));
  }
}

// ---------------------------------------------------------------- final LN + column-sum partials
__global__ void ln_colsum(const float* __restrict__ h, const float* __restrict__ g,
                          const float* __restrict__ bb, float* __restrict__ partial) {
  int blk = blockIdx.x;
  int b = blk / 64, grp = blk % 64;
  int wave = threadIdx.x >> 6, lane = threadIdx.x & 63;
  float a0 = 0.f, a1 = 0.f;
  float g0 = g[lane], g1 = g[lane + 64], b0 = bb[lane], b1 = bb[lane + 64];
  for (int j = 0; j < 16; j++) {
    int row = b * L + grp * 64 + wave * 16 + j;
    const float* p = h + (size_t)row * E;
    float x0 = p[lane], x1 = p[lane + 64];
    float s1 = x0 + x1, s2 = x0 * x0 + x1 * x1;
    #pragma unroll
    for (int off = 32; off > 0; off >>= 1) {
      s1 += __shfl_xor(s1, off);
      s2 += __shfl_xor(s2, off);
    }
    float m = s1 * (1.0f / E);
    float var = s2 * (1.0f / E) - m * m;
    float inv = rsqrtf(var + 1e-5f);
    a0 += (x0 - m) * inv * g0 + b0;
    a1 += (x1 - m) * inv * g1 + b1;
  }
  __shared__ float red[4][128];
  red[wave][lane] = a0;
  red[wave][lane + 64] = a1;
  __syncthreads();
  if (wave == 0) {
    #pragma unroll
    for (int half = 0; half < 2; half++) {
      int e = lane + half * 64;
      float s = red[0][e] + red[1][e] + red[2][e] + red[3][e];
      partial[(size_t)blk * E + e] = s;
    }
  }
}

// ---------------------------------------------------------------- final FC (reduce partials + project)
__global__ void fc_kernel(const float* __restrict__ partial, const float* __restrict__ fcw,
                          const float* __restrict__ fcb, float* __restrict__ out) {
  __shared__ float hm[BATCH * E];
  for (int idx = threadIdx.x; idx < BATCH * E; idx += 256) {
    int b = idx >> 7, e = idx & 127;
    float s = 0.f;
    for (int g2 = 0; g2 < 64; g2++) s += partial[(size_t)(b * 64 + g2) * E + e];
    hm[idx] = s;
  }
  __syncthreads();
  int i = threadIdx.x;
  if (i < BATCH * NC) {
    int b = i / NC, o = i % NC;
    float acc = 0.f;
    for (int e = 0; e < E; e++) acc += hm[b * E + e] * fcw[o * E + e];
    out[i] = acc * (1.f / L) + fcb[o];
  }
}

// ---------------------------------------------------------------- launch
extern "C" void kernel_launch(void* const* d_in, const int* in_sizes, int n_in,
                              void* d_out, int out_size, void* d_ws, size_t ws_size,
                              hipStream_t stream) {
  const float* x      = (const float*)d_in[0];
  const int*   oh     = (const int*)d_in[1];
  const int*   ot     = (const int*)d_in[2];
  const float* pe_w   = (const float*)d_in[3];
  const float* pe_b   = (const float*)d_in[4];
  const float* gamma  = (const float*)d_in[5];
  const float* beta   = (const float*)d_in[6];
  const float* ln_g   = (const float*)d_in[7];
  const float* ln_b   = (const float*)d_in[8];
  const float* inproj = (const float*)d_in[9];
  const float* conv_w = (const float*)d_in[10];
  const float* conv_b = (const float*)d_in[11];
  const float* xproj  = (const float*)d_in[12];
  const float* dtw    = (const float*)d_in[13];
  const float* dtb    = (const float*)d_in[14];
  const float* A_log  = (const float*)d_in[15];
  const float* Dp     = (const float*)d_in[16];
  const float* outw   = (const float*)d_in[17];
  const float* hn_g   = (const float*)d_in[18];
  const float* hn_b   = (const float*)d_in[19];
  const float* fc_w   = (const float*)d_in[20];
  const float* fc_b   = (const float*)d_in[21];
  float* out = (float*)d_out;

  char* ws = (char*)d_ws;
  size_t off = 0;
  auto alloc = [&](size_t bytes) { size_t o = off; off += (bytes + 255) & ~(size_t)255; return o; };
  float* h     = (float*)(ws + alloc((size_t)ROWS * E * 4));              // 8 MB
  u16*   xnhi  = (u16*)  (ws + alloc((size_t)ROWS * E * 2));              // 4 MB
  u16*   xnlo  = (u16*)  (ws + alloc((size_t)ROWS * E * 2));              // 4 MB
  float* uz    = (float*)(ws + alloc((size_t)ROWS * 2 * DI * 4));         // 32 MB
  u16*   yhi   = (u16*)  (ws + alloc((size_t)ROWS * DI * 2));             // 8 MB
  u16*   ylo   = (u16*)  (ws + alloc((size_t)ROWS * DI * 2));             // 8 MB
  float* hloc  = (float*)(ws + alloc((size_t)BATCH * NCH * DI * DS * 4)); // 16.8 MB
  float* sumd  = (float*)(ws + alloc((size_t)BATCH * NCH * DI * 4));      // 1 MB
  u16*   wihi  = (u16*)  (ws + alloc((size_t)NBLK * 2 * DI * E * 2));     // 256 KB
  u16*   wilo  = (u16*)  (ws + alloc((size_t)NBLK * 2 * DI * E * 2));     // 256 KB
  u16*   wohi  = (u16*)  (ws + alloc((size_t)NBLK * E * DI * 2));         // 128 KB
  u16*   wolo  = (u16*)  (ws + alloc((size_t)NBLK * E * DI * 2));         // 128 KB
  float* partial = (float*)(ws + alloc((size_t)BATCH * 64 * E * 4));      // 128 KB
  float* hinit = hloc;    // passB: same-thread read-before-write per element

  embed_ln_split<<<ROWS / 4, 256, 0, stream>>>(x, oh, ot, pe_w, pe_b, gamma, beta,
                                               ln_g, ln_b, h, xnhi, xnlo);
  split_all<<<(NBLK * 2 * DI * E + NBLK * E * DI + 255) / 256, 256, 0, stream>>>(
      inproj, outw, wihi, wilo, wohi, wolo);

  for (int i = 0; i < NBLK; i++) {
    if (i > 0)
      ln_split_kernel<<<ROWS / 4, 256, 0, stream>>>(h, xnhi, xnlo, ln_g + i * E, ln_b + i * E);

    // uz = xn @ inproj^T   (M=ROWS, N=2*DI=512, K=E=128)
    dim3 g1(ROWS / 128, (2 * DI) / 128);
    mfma_gemm_lds<128, 0><<<g1, 256, 0, stream>>>(xnhi, xnlo,
                                                  wihi + (size_t)i * 2 * DI * E, wilo + (size_t)i * 2 * DI * E,
                                                  uz, ROWS, 2 * DI, E, 2 * DI);

    scan_fusedA<<<BATCH * NCH, 256, 0, stream>>>(uz, xproj + (size_t)i * XDW * DI,
                                                 conv_w + i * DI * DCV, conv_b + i * DI,
                                                 dtw + (size_t)i * DI * DRR, dtb + i * DI,
                                                 A_log + (size_t)i * DI * DS, hloc, sumd);
    scan_passB<<<BATCH * (DI / 4), 64, 0, stream>>>(A_log + (size_t)i * DI * DS, hloc, sumd, hinit);
    scan_fusedC<<<BATCH * NCH, 256, 0, stream>>>(uz, xproj + (size_t)i * XDW * DI,
                                                 conv_w + i * DI * DCV, conv_b + i * DI,
                                                 dtw + (size_t)i * DI * DRR, dtb + i * DI,
                                                 A_log + (size_t)i * DI * DS, Dp + i * DI,
                                                 hinit, yhi, ylo);

    // h += y @ outproj^T   (M=ROWS, N=E=128, K=DI=256)
    dim3 g4(ROWS / 128, E / 64);
    mfma_gemm_lds<64, 1><<<g4, 256, 0, stream>>>(yhi, ylo,
                                                 wohi + (size_t)i * E * DI, wolo + (size_t)i * E * DI,
                                                 h, ROWS, E, DI, E);
  }

  ln_colsum<<<BATCH * 64, 256, 0, stream>>>(h, hn_g, hn_b, partial);
  fc_kernel<<<1, 256, 0, stream>>>(partial, fc_w, fc_b, out);
}

// Round 13
// 426.445 us; speedup vs baseline: 1.4838x; 1.4838x over previous
//
#include <hip/hip_runtime.h>
#include <hip/hip_bf16.h>
#include <math.h>

// Problem constants (CompactPointMamba: B=4, N=2048, E=128)
#define BATCH 4
#define NPTS  2048
#define L     4096      // 2*NPTS after concat of hilbert/trans orders
#define E     128
#define DI    256       // E*EXP
#define DS    16
#define DRR   8         // (E+15)//16
#define DCV   4
#define NBLK  2
#define NC    40
#define XDW   40        // DR + 2*DS
#define ROWS  (BATCH*L) // 16384
#define CH    16        // scan chunk length
#define NCH   256       // L / CH

typedef unsigned short u16;
typedef short short8 __attribute__((ext_vector_type(8)));
typedef float f32x4v __attribute__((ext_vector_type(4)));

// bf16 round-to-nearest-even helpers
__device__ __forceinline__ u16 f2bf(float x) {
  unsigned u = __float_as_uint(x);
  u = u + 0x7FFFu + ((u >> 16) & 1u);
  return (u16)(u >> 16);
}
__device__ __forceinline__ float bf2f(u16 h) {
  return __uint_as_float(((unsigned)h) << 16);
}
// fast softplus: ln(1+e^x) = ln2 * log2(1 + 2^(x*log2e))
__device__ __forceinline__ float softplusf(float x) {
  if (x > 20.f) return x;
  float t = __builtin_amdgcn_exp2f(x * 1.44269504f);
  return 0.69314718f * __builtin_amdgcn_logf(1.f + t);
}

// ---------------------------------------------------------------- embed + LN(block0) + split, row per wave
__global__ void embed_ln_split(const float* __restrict__ x,
                               const int* __restrict__ oh, const int* __restrict__ ot,
                               const float* __restrict__ pe_w, const float* __restrict__ pe_b,
                               const float* __restrict__ gamma, const float* __restrict__ beta,
                               const float* __restrict__ g, const float* __restrict__ bb,
                               float* __restrict__ h, u16* __restrict__ dhi, u16* __restrict__ dlo) {
  int wave = threadIdx.x >> 6;
  int lane = threadIdx.x & 63;
  int row = blockIdx.x * 4 + wave;        // b*L + n
  int n = row % L;
  int b = row / L;
  int gi = (n >= NPTS) ? 1 : 0;
  int nn = n - gi * NPTS;
  int src = gi ? ot[b * NPTS + nn] : oh[b * NPTS + nn];
  const float* xp = x + ((size_t)b * NPTS + src) * 3;
  float p0 = xp[0], p1 = xp[1], p2 = xp[2];
  int e0 = lane, e1 = lane + 64;
  float v0 = pe_b[e0] + p0 * pe_w[e0 * 3] + p1 * pe_w[e0 * 3 + 1] + p2 * pe_w[e0 * 3 + 2];
  float v1 = pe_b[e1] + p0 * pe_w[e1 * 3] + p1 * pe_w[e1 * 3 + 1] + p2 * pe_w[e1 * 3 + 2];
  v0 = v0 * gamma[gi * E + e0] + beta[gi * E + e0];
  v1 = v1 * gamma[gi * E + e1] + beta[gi * E + e1];
  size_t base = (size_t)row * E;
  h[base + e0] = v0;
  h[base + e1] = v1;
  // LN
  float s1 = v0 + v1, s2 = v0 * v0 + v1 * v1;
  #pragma unroll
  for (int off = 32; off > 0; off >>= 1) {
    s1 += __shfl_xor(s1, off);
    s2 += __shfl_xor(s2, off);
  }
  float m = s1 * (1.0f / E);
  float var = s2 * (1.0f / E) - m * m;
  float inv = rsqrtf(var + 1e-5f);
  float o0 = (v0 - m) * inv * g[e0] + bb[e0];
  float o1 = (v1 - m) * inv * g[e1] + bb[e1];
  u16 h0 = f2bf(o0), h1 = f2bf(o1);
  dhi[base + e0] = h0; dhi[base + e1] = h1;
  dlo[base + e0] = f2bf(o0 - bf2f(h0));
  dlo[base + e1] = f2bf(o1 - bf2f(h1));
}

// ---------------------------------------------------------------- split all weights (inproj + outw) in one dispatch
__global__ void split_all(const float* __restrict__ inproj, const float* __restrict__ outw,
                          u16* __restrict__ wihi, u16* __restrict__ wilo,
                          u16* __restrict__ wohi, u16* __restrict__ wolo) {
  const int n1 = NBLK * 2 * DI * E;
  const int n2 = NBLK * E * DI;
  int i = blockIdx.x * 256 + threadIdx.x;
  if (i < n1) {
    float v = inproj[i];
    u16 h = f2bf(v);
    wihi[i] = h; wilo[i] = f2bf(v - bf2f(h));
  } else if (i < n1 + n2) {
    int j = i - n1;
    float v = outw[j];
    u16 h = f2bf(v);
    wohi[j] = h; wolo[j] = f2bf(v - bf2f(h));
  }
}

// ---------------------------------------------------------------- layernorm -> bf16 hi/lo split (block 1)
__global__ void ln_split_kernel(const float* __restrict__ src, u16* __restrict__ dhi,
                                u16* __restrict__ dlo, const float* __restrict__ g,
                                const float* __restrict__ bb) {
  int wave = threadIdx.x >> 6;
  int lane = threadIdx.x & 63;
  int row = blockIdx.x * 4 + wave;
  const float* p = src + (size_t)row * E;
  float x0 = p[lane], x1 = p[lane + 64];
  float s1 = x0 + x1, s2 = x0 * x0 + x1 * x1;
  #pragma unroll
  for (int off = 32; off > 0; off >>= 1) {
    s1 += __shfl_xor(s1, off);
    s2 += __shfl_xor(s2, off);
  }
  float m = s1 * (1.0f / E);
  float v = s2 * (1.0f / E) - m * m;
  float inv = rsqrtf(v + 1e-5f);
  float v0 = (x0 - m) * inv * g[lane]      + bb[lane];
  float v1 = (x1 - m) * inv * g[lane + 64] + bb[lane + 64];
  size_t base = (size_t)row * E;
  u16 h0 = f2bf(v0), h1 = f2bf(v1);
  dhi[base + lane]      = h0;
  dhi[base + lane + 64] = h1;
  dlo[base + lane]      = f2bf(v0 - bf2f(h0));
  dlo[base + lane + 64] = f2bf(v1 - bf2f(h1));
}

// ---------------------------------------------------------------- LDS-staged split-bf16 MFMA GEMM
template<int BN, int ACC>
__global__ __launch_bounds__(256)
void mfma_gemm_lds(const u16* __restrict__ Ahi, const u16* __restrict__ Alo,
                   const u16* __restrict__ Bhi, const u16* __restrict__ Blo,
                   float* __restrict__ C, int M, int N, int K, int ldc) {
  constexpr int BM = 128, BK = 64, PITCH = 72;
  constexpr int MSUB = (BN == 128) ? 4 : 2;
  constexpr int NSUB = 4;
  __shared__ u16 sA[2][BM][PITCH];
  __shared__ u16 sB[2][BN][PITCH];
  int tid = threadIdx.x;
  int wave = tid >> 6, lane = tid & 63, quad = lane >> 4, l16 = lane & 15;
  int rowBase = blockIdx.x * BM, colBase = blockIdx.y * BN;
  int wrow = (BN == 128) ? (wave >> 1) * 64 : wave * 32;
  int wcol = (BN == 128) ? (wave & 1) * 64 : 0;
  f32x4v acc[MSUB][NSUB] = {};
  for (int k0 = 0; k0 < K; k0 += BK) {
    #pragma unroll
    for (int hl = 0; hl < 2; hl++) {
      const u16* srcA = hl ? Alo : Ahi;
      #pragma unroll
      for (int c = 0; c < BM * 8 / 256; c++) {
        int ch = c * 256 + tid;
        int row = ch >> 3, kc = ch & 7;
        float4 v = *(const float4*)(srcA + (size_t)(rowBase + row) * K + k0 + kc * 8);
        *(float4*)&sA[hl][row][kc * 8] = v;
      }
      const u16* srcB = hl ? Blo : Bhi;
      #pragma unroll
      for (int c = 0; c < BN * 8 / 256; c++) {
        int ch = c * 256 + tid;
        int row = ch >> 3, kc = ch & 7;
        float4 v = *(const float4*)(srcB + (size_t)(colBase + row) * K + k0 + kc * 8);
        *(float4*)&sB[hl][row][kc * 8] = v;
      }
    }
    __syncthreads();
    short8 afh[MSUB][2], afl[MSUB][2];
    #pragma unroll
    for (int i = 0; i < MSUB; i++)
      #pragma unroll
      for (int kf = 0; kf < 2; kf++) {
        afh[i][kf] = *(const short8*)&sA[0][wrow + i * 16 + l16][kf * 32 + quad * 8];
        afl[i][kf] = *(const short8*)&sA[1][wrow + i * 16 + l16][kf * 32 + quad * 8];
      }
    #pragma unroll
    for (int j = 0; j < NSUB; j++)
      #pragma unroll
      for (int kf = 0; kf < 2; kf++) {
        short8 bh = *(const short8*)&sB[0][wcol + j * 16 + l16][kf * 32 + quad * 8];
        short8 bl = *(const short8*)&sB[1][wcol + j * 16 + l16][kf * 32 + quad * 8];
        #pragma unroll
        for (int i = 0; i < MSUB; i++) {
          acc[i][j] = __builtin_amdgcn_mfma_f32_16x16x32_bf16(afh[i][kf], bh, acc[i][j], 0, 0, 0);
          acc[i][j] = __builtin_amdgcn_mfma_f32_16x16x32_bf16(afh[i][kf], bl, acc[i][j], 0, 0, 0);
          acc[i][j] = __builtin_amdgcn_mfma_f32_16x16x32_bf16(afl[i][kf], bh, acc[i][j], 0, 0, 0);
        }
      }
    __syncthreads();
  }
  int orow0 = rowBase + wrow + quad * 4;
  #pragma unroll
  for (int i = 0; i < MSUB; i++) {
    #pragma unroll
    for (int j = 0; j < NSUB; j++) {
      int cc = colBase + wcol + j * 16 + l16;
      #pragma unroll
      for (int r = 0; r < 4; r++) {
        size_t idx = (size_t)(orow0 + i * 16 + r) * ldc + cc;
        if (ACC) C[idx] += acc[i][j][r];
        else     C[idx] = acc[i][j][r];
      }
    }
  }
}

// ---------------------------------------------------------------- generic fp32 GEMM (xproj only)
__global__ void gemm_bt(const float* __restrict__ A, int lda,
                        const float* __restrict__ B, int ldb,
                        float* __restrict__ C, int ldc,
                        int M, int N, int K) {
  __shared__ float As[16][68];
  __shared__ float Bs[16][68];
  int tx = threadIdx.x % 16, ty = threadIdx.x / 16;
  int rowBase = blockIdx.x * 64, colBase = blockIdx.y * 64;
  float acc[4][4] = {};
  int lr = threadIdx.x / 4;
  int lc = (threadIdx.x % 4) * 4;
  for (int k0 = 0; k0 < K; k0 += 16) {
    int ar = rowBase + lr;
    {
      float4 v = *(const float4*)&A[(size_t)ar * lda + k0 + lc];
      As[lc + 0][lr] = v.x; As[lc + 1][lr] = v.y;
      As[lc + 2][lr] = v.z; As[lc + 3][lr] = v.w;
    }
    int br = colBase + lr;
    if (br < N) {
      float4 v = *(const float4*)&B[(size_t)br * ldb + k0 + lc];
      Bs[lc + 0][lr] = v.x; Bs[lc + 1][lr] = v.y;
      Bs[lc + 2][lr] = v.z; Bs[lc + 3][lr] = v.w;
    } else {
      #pragma unroll
      for (int j = 0; j < 4; j++) Bs[lc + j][lr] = 0.f;
    }
    __syncthreads();
    #pragma unroll
    for (int kk = 0; kk < 16; kk++) {
      float4 a4 = *(const float4*)&As[kk][ty * 4];
      float4 b4 = *(const float4*)&Bs[kk][tx * 4];
      float a[4] = {a4.x, a4.y, a4.z, a4.w};
      float bv[4] = {b4.x, b4.y, b4.z, b4.w};
      #pragma unroll
      for (int i = 0; i < 4; i++)
        #pragma unroll
        for (int j = 0; j < 4; j++) acc[i][j] += a[i] * bv[j];
    }
    __syncthreads();
  }
  #pragma unroll
  for (int i = 0; i < 4; i++) {
    int r = rowBase + ty * 4 + i;
    #pragma unroll
    for (int j = 0; j < 4; j++) {
      int c = colBase + tx * 4 + j;
      if (c < N) C[(size_t)r * ldc + c] = acc[i][j];
    }
  }
}

// ---------------------------------------------------------------- causal depthwise conv + silu, 16 rows/thread
// u in uz (row stride 2*DI, cols 0..DI-1). grid: ROWS/16 blocks x 256 threads.
__global__ void conv_silu16(const float* __restrict__ uz, const float* __restrict__ cw,
                            const float* __restrict__ cb, float* __restrict__ uc) {
  int d = threadIdx.x;
  int r0 = blockIdx.x * 16;
  int b = r0 / L;
  int t0 = r0 % L;
  float w0 = cw[d * DCV + 0], w1 = cw[d * DCV + 1], w2 = cw[d * DCV + 2], w3 = cw[d * DCV + 3];
  float bias = cb[d];
  float uwin[19];
  #pragma unroll
  for (int j = 0; j < 19; j++) {
    int t = t0 + j - 3;
    uwin[j] = (t >= 0) ? uz[((size_t)b * L + t) * (2 * DI) + d] : 0.f;
  }
  #pragma unroll
  for (int j = 0; j < 16; j++) {
    float a = bias + w0 * uwin[j] + w1 * uwin[j + 1] + w2 * uwin[j + 2] + w3 * uwin[j + 3];
    uc[((size_t)r0 + j) * DI + d] = a / (1.f + __expf(-a));
  }
}

// ---------------------------------------------------------------- scan pass A (dtproj+softplus fused)
// hloc layout: [b][c][d][s]  (coalesced for threads=d); sumd: [b][c][d]
__global__ __launch_bounds__(256, 4)
void scan_passA(const float* __restrict__ uc, const float* __restrict__ xdbl,
                const float* __restrict__ dtw, const float* __restrict__ dtb,
                const float* __restrict__ A_log,
                float* __restrict__ hloc, float* __restrict__ sumd) {
  int b = blockIdx.x / NCH, c = blockIdx.x % NCH;
  int d = threadIdx.x;
  __shared__ float Bsh[CH][DS];
  __shared__ float Dsh[CH][DRR];
  {
    int i = threadIdx.x;
    int t0 = i >> 4, s = i & 15;
    size_t rb = ((size_t)b * L + c * CH + t0) * XDW;
    Bsh[t0][s] = xdbl[rb + DRR + s];
    if (i < CH * DRR) {
      int td = i >> 3, q = i & 7;
      Dsh[td][q] = xdbl[((size_t)b * L + c * CH + td) * XDW + q];
    }
  }
  // prefetch global while LDS staging is in flight
  float ut[CH];
  const float* uc_p = uc + ((size_t)b * L + c * CH) * DI + d;
  #pragma unroll
  for (int t0 = 0; t0 < CH; t0++) ut[t0] = uc_p[(size_t)t0 * DI];
  float Av[DS];
  #pragma unroll
  for (int s = 0; s < DS; s++) Av[s] = -__expf(A_log[d * DS + s]);
  float4 w0 = *(const float4*)(dtw + d * DRR);
  float4 w1 = *(const float4*)(dtw + d * DRR + 4);
  float bias = dtb[d];
  __syncthreads();
  float dl[CH];
  float sd = 0.f;
  #pragma unroll
  for (int t0 = 0; t0 < CH; t0++) {
    float4 D0 = *(const float4*)&Dsh[t0][0];
    float4 D1 = *(const float4*)&Dsh[t0][4];
    float v = bias + D0.x * w0.x + D0.y * w0.y + D0.z * w0.z + D0.w * w0.w
                   + D1.x * w1.x + D1.y * w1.y + D1.z * w1.z + D1.w * w1.w;
    dl[t0] = softplusf(v);
    sd += dl[t0];
  }
  float st[DS] = {};
  #pragma unroll
  for (int t0 = 0; t0 < CH; t0++) {
    float du = dl[t0] * ut[t0];
    float4 B0 = *(const float4*)&Bsh[t0][0];
    float4 B1 = *(const float4*)&Bsh[t0][4];
    float4 B2 = *(const float4*)&Bsh[t0][8];
    float4 B3 = *(const float4*)&Bsh[t0][12];
    float Bv[DS] = {B0.x, B0.y, B0.z, B0.w, B1.x, B1.y, B1.z, B1.w,
                    B2.x, B2.y, B2.z, B2.w, B3.x, B3.y, B3.z, B3.w};
    #pragma unroll
    for (int s = 0; s < DS; s++) {
      float a = __expf(dl[t0] * Av[s]);
      st[s] = a * st[s] + du * Bv[s];
    }
  }
  size_t base = (((size_t)b * NCH + c) * DI + d) * DS;
  *(float4*)&hloc[base + 0]  = float4{st[0], st[1], st[2], st[3]};
  *(float4*)&hloc[base + 4]  = float4{st[4], st[5], st[6], st[7]};
  *(float4*)&hloc[base + 8]  = float4{st[8], st[9], st[10], st[11]};
  *(float4*)&hloc[base + 12] = float4{st[12], st[13], st[14], st[15]};
  sumd[((size_t)b * NCH + c) * DI + d] = sd;
}

// ---------------------------------------------------------------- scan pass B: coalesced serial scan, depth-8 prefetch
#define PB_G 8
__global__ __launch_bounds__(64)
void scan_passB(const float* __restrict__ A_log, const float* __restrict__ hloc,
                const float* __restrict__ sumd, float* __restrict__ hinit) {
  int tid = threadIdx.x;
  int dgroup = blockIdx.x % (DI / 4);
  int b = blockIdx.x / (DI / 4);
  int d = dgroup * 4 + (tid >> 4);
  int s = tid & 15;
  float Av = -__expf(A_log[d * DS + s]);
  size_t off = (size_t)b * NCH * DI * DS + dgroup * 64 + tid;
  size_t soff = (size_t)b * NCH * DI + d;
  const size_t HST = (size_t)DI * DS;
  float bv[PB_G], sd[PB_G], bvn[PB_G], sdn[PB_G];
  #pragma unroll
  for (int j = 0; j < PB_G; j++) {
    bv[j] = hloc[off + j * HST];
    sd[j] = sumd[soff + j * DI];
  }
  float X = 0.f;
  for (int g = 0; g < NCH / PB_G; g++) {
    if (g + 1 < NCH / PB_G) {
      #pragma unroll
      for (int j = 0; j < PB_G; j++) {
        bvn[j] = hloc[off + (j + PB_G) * HST];
        sdn[j] = sumd[soff + (j + PB_G) * DI];
      }
    }
    #pragma unroll
    for (int j = 0; j < PB_G; j++) {
      float a = __expf(Av * sd[j]);
      hinit[off + j * HST] = X;
      X = a * X + bv[j];
    }
    #pragma unroll
    for (int j = 0; j < PB_G; j++) { bv[j] = bvn[j]; sd[j] = sdn[j]; }
    off += PB_G * HST;
    soff += PB_G * DI;
  }
}

// ---------------------------------------------------------------- scan pass C (dtproj fused; y -> bf16 hi/lo)
__global__ __launch_bounds__(256, 4)
void scan_passC(const float* __restrict__ uc, const float* __restrict__ xdbl,
                const float* __restrict__ dtw, const float* __restrict__ dtb,
                const float* __restrict__ A_log, const float* __restrict__ Dp,
                const float* __restrict__ uz, const float* __restrict__ hinit,
                u16* __restrict__ yhi, u16* __restrict__ ylo) {
  int b = blockIdx.x / NCH, c = blockIdx.x % NCH;
  int d = threadIdx.x;
  __shared__ float Bsh[CH][DS];
  __shared__ float Csh[CH][DS];
  __shared__ float Dsh[CH][DRR];
  {
    int i = threadIdx.x;
    int t0 = i >> 4, s = i & 15;
    size_t rb = ((size_t)b * L + c * CH + t0) * XDW;
    Bsh[t0][s] = xdbl[rb + DRR + s];
    Csh[t0][s] = xdbl[rb + DRR + DS + s];
    if (i < CH * DRR) {
      int td = i >> 3, q = i & 7;
      Dsh[td][q] = xdbl[((size_t)b * L + c * CH + td) * XDW + q];
    }
  }
  // prefetch
  float ut[CH];
  const float* uc_p = uc + ((size_t)b * L + c * CH) * DI + d;
  #pragma unroll
  for (int t0 = 0; t0 < CH; t0++) ut[t0] = uc_p[(size_t)t0 * DI];
  float st[DS];
  size_t hbase = (((size_t)b * NCH + c) * DI + d) * DS;
  {
    float4 h0 = *(const float4*)&hinit[hbase + 0];
    float4 h1 = *(const float4*)&hinit[hbase + 4];
    float4 h2 = *(const float4*)&hinit[hbase + 8];
    float4 h3 = *(const float4*)&hinit[hbase + 12];
    st[0]=h0.x; st[1]=h0.y; st[2]=h0.z; st[3]=h0.w;
    st[4]=h1.x; st[5]=h1.y; st[6]=h1.z; st[7]=h1.w;
    st[8]=h2.x; st[9]=h2.y; st[10]=h2.z; st[11]=h2.w;
    st[12]=h3.x; st[13]=h3.y; st[14]=h3.z; st[15]=h3.w;
  }
  float Av[DS];
  #pragma unroll
  for (int s = 0; s < DS; s++) Av[s] = -__expf(A_log[d * DS + s]);
  float4 w0 = *(const float4*)(dtw + d * DRR);
  float4 w1 = *(const float4*)(dtw + d * DRR + 4);
  float bias = dtb[d];
  float Dv = Dp[d];
  const float* z_p = uz + ((size_t)b * L + c * CH) * (2 * DI) + DI + d;
  size_t ybase = ((size_t)b * L + c * CH) * DI + d;
  __syncthreads();
  float dl[CH];
  #pragma unroll
  for (int t0 = 0; t0 < CH; t0++) {
    float4 D0 = *(const float4*)&Dsh[t0][0];
    float4 D1 = *(const float4*)&Dsh[t0][4];
    float v = bias + D0.x * w0.x + D0.y * w0.y + D0.z * w0.z + D0.w * w0.w
                   + D1.x * w1.x + D1.y * w1.y + D1.z * w1.z + D1.w * w1.w;
    dl[t0] = softplusf(v);
  }
  float znext = z_p[0];
  #pragma unroll
  for (int t0 = 0; t0 < CH; t0++) {
    float zz = znext;
    if (t0 < CH - 1) znext = z_p[(size_t)(t0 + 1) * (2 * DI)];
    float du = dl[t0] * ut[t0];
    float acc = Dv * ut[t0];
    float4 B0 = *(const float4*)&Bsh[t0][0];
    float4 B1 = *(const float4*)&Bsh[t0][4];
    float4 B2 = *(const float4*)&Bsh[t0][8];
    float4 B3 = *(const float4*)&Bsh[t0][12];
    float4 C0 = *(const float4*)&Csh[t0][0];
    float4 C1 = *(const float4*)&Csh[t0][4];
    float4 C2 = *(const float4*)&Csh[t0][8];
    float4 C3 = *(const float4*)&Csh[t0][12];
    float Bv[DS] = {B0.x, B0.y, B0.z, B0.w, B1.x, B1.y, B1.z, B1.w,
                    B2.x, B2.y, B2.z, B2.w, B3.x, B3.y, B3.z, B3.w};
    float Cv[DS] = {C0.x, C0.y, C0.z, C0.w, C1.x, C1.y, C1.z, C1.w,
                    C2.x, C2.y, C2.z, C2.w, C3.x, C3.y, C3.z, C3.w};
    #pragma unroll
    for (int s = 0; s < DS; s++) {
      float a = __expf(dl[t0] * Av[s]);
      st[s] = a * st[s] + du * Bv[s];
      acc += st[s] * Cv[s];
    }
    float v = acc * (zz / (1.f + __expf(-zz)));
    u16 hh = f2bf(v);
    yhi[ybase + (size_t)t0 * DI] = hh;
    ylo[ybase + (size_t)t0 * DI] = f2bf(v - bf2f(hh));
  }
}

// ---------------------------------------------------------------- final LN + column-sum partials
__global__ void ln_colsum(const float* __restrict__ h, const float* __restrict__ g,
                          const float* __restrict__ bb, float* __restrict__ partial) {
  int blk = blockIdx.x;
  int b = blk / 64, grp = blk % 64;
  int wave = threadIdx.x >> 6, lane = threadIdx.x & 63;
  float a0 = 0.f, a1 = 0.f;
  float g0 = g[lane], g1 = g[lane + 64], b0 = bb[lane], b1 = bb[lane + 64];
  for (int j = 0; j < 16; j++) {
    int row = b * L + grp * 64 + wave * 16 + j;
    const float* p = h + (size_t)row * E;
    float x0 = p[lane], x1 = p[lane + 64];
    float s1 = x0 + x1, s2 = x0 * x0 + x1 * x1;
    #pragma unroll
    for (int off = 32; off > 0; off >>= 1) {
      s1 += __shfl_xor(s1, off);
      s2 += __shfl_xor(s2, off);
    }
    float m = s1 * (1.0f / E);
    float var = s2 * (1.0f / E) - m * m;
    float inv = rsqrtf(var + 1e-5f);
    a0 += (x0 - m) * inv * g0 + b0;
    a1 += (x1 - m) * inv * g1 + b1;
  }
  __shared__ float red[4][128];
  red[wave][lane] = a0;
  red[wave][lane + 64] = a1;
  __syncthreads();
  if (wave == 0) {
    #pragma unroll
    for (int half = 0; half < 2; half++) {
      int e = lane + half * 64;
      float s = red[0][e] + red[1][e] + red[2][e] + red[3][e];
      partial[(size_t)blk * E + e] = s;
    }
  }
}

// ---------------------------------------------------------------- final FC (reduce partials + project)
__global__ void fc_kernel(const float* __restrict__ partial, const float* __restrict__ fcw,
                          const float* __restrict__ fcb, float* __restrict__ out) {
  __shared__ float hm[BATCH * E];
  for (int idx = threadIdx.x; idx < BATCH * E; idx += 256) {
    int b = idx >> 7, e = idx & 127;
    float s = 0.f;
    for (int g2 = 0; g2 < 64; g2++) s += partial[(size_t)(b * 64 + g2) * E + e];
    hm[idx] = s;
  }
  __syncthreads();
  int i = threadIdx.x;
  if (i < BATCH * NC) {
    int b = i / NC, o = i % NC;
    float acc = 0.f;
    for (int e = 0; e < E; e++) acc += hm[b * E + e] * fcw[o * E + e];
    out[i] = acc * (1.f / L) + fcb[o];
  }
}

// ---------------------------------------------------------------- launch
extern "C" void kernel_launch(void* const* d_in, const int* in_sizes, int n_in,
                              void* d_out, int out_size, void* d_ws, size_t ws_size,
                              hipStream_t stream) {
  const float* x      = (const float*)d_in[0];
  const int*   oh     = (const int*)d_in[1];
  const int*   ot     = (const int*)d_in[2];
  const float* pe_w   = (const float*)d_in[3];
  const float* pe_b   = (const float*)d_in[4];
  const float* gamma  = (const float*)d_in[5];
  const float* beta   = (const float*)d_in[6];
  const float* ln_g   = (const float*)d_in[7];
  const float* ln_b   = (const float*)d_in[8];
  const float* inproj = (const float*)d_in[9];
  const float* conv_w = (const float*)d_in[10];
  const float* conv_b = (const float*)d_in[11];
  const float* xproj  = (const float*)d_in[12];
  const float* dtw    = (const float*)d_in[13];
  const float* dtb    = (const float*)d_in[14];
  const float* A_log  = (const float*)d_in[15];
  const float* Dp     = (const float*)d_in[16];
  const float* outw   = (const float*)d_in[17];
  const float* hn_g   = (const float*)d_in[18];
  const float* hn_b   = (const float*)d_in[19];
  const float* fc_w   = (const float*)d_in[20];
  const float* fc_b   = (const float*)d_in[21];
  float* out = (float*)d_out;

  char* ws = (char*)d_ws;
  size_t off = 0;
  auto alloc = [&](size_t bytes) { size_t o = off; off += (bytes + 255) & ~(size_t)255; return o; };
  float* h     = (float*)(ws + alloc((size_t)ROWS * E * 4));              // 8 MB
  u16*   xnhi  = (u16*)  (ws + alloc((size_t)ROWS * E * 2));              // 4 MB
  u16*   xnlo  = (u16*)  (ws + alloc((size_t)ROWS * E * 2));              // 4 MB
  float* uz    = (float*)(ws + alloc((size_t)ROWS * 2 * DI * 4));         // 32 MB
  float* uc    = (float*)(ws + alloc((size_t)ROWS * DI * 4));             // 16 MB
  float* xdbl  = (float*)(ws + alloc((size_t)ROWS * XDW * 4));            // 2.6 MB
  u16*   yhi   = (u16*)  (ws + alloc((size_t)ROWS * DI * 2));             // 8 MB
  u16*   ylo   = (u16*)  (ws + alloc((size_t)ROWS * DI * 2));             // 8 MB
  float* hloc  = (float*)(ws + alloc((size_t)BATCH * NCH * DI * DS * 4)); // 16.8 MB
  float* sumd  = (float*)(ws + alloc((size_t)BATCH * NCH * DI * 4));      // 1 MB
  u16*   wihi  = (u16*)  (ws + alloc((size_t)NBLK * 2 * DI * E * 2));     // 256 KB
  u16*   wilo  = (u16*)  (ws + alloc((size_t)NBLK * 2 * DI * E * 2));     // 256 KB
  u16*   wohi  = (u16*)  (ws + alloc((size_t)NBLK * E * DI * 2));         // 128 KB
  u16*   wolo  = (u16*)  (ws + alloc((size_t)NBLK * E * DI * 2));         // 128 KB
  float* partial = (float*)(ws + alloc((size_t)BATCH * 64 * E * 4));      // 128 KB
  float* hinit = hloc;    // passB: same-thread read-before-write per element

  embed_ln_split<<<ROWS / 4, 256, 0, stream>>>(x, oh, ot, pe_w, pe_b, gamma, beta,
                                               ln_g, ln_b, h, xnhi, xnlo);
  split_all<<<(NBLK * 2 * DI * E + NBLK * E * DI + 255) / 256, 256, 0, stream>>>(
      inproj, outw, wihi, wilo, wohi, wolo);

  for (int i = 0; i < NBLK; i++) {
    if (i > 0)
      ln_split_kernel<<<ROWS / 4, 256, 0, stream>>>(h, xnhi, xnlo, ln_g + i * E, ln_b + i * E);

    // uz = xn @ inproj^T   (M=ROWS, N=2*DI=512, K=E=128)
    dim3 g1(ROWS / 128, (2 * DI) / 128);
    mfma_gemm_lds<128, 0><<<g1, 256, 0, stream>>>(xnhi, xnlo,
                                                  wihi + (size_t)i * 2 * DI * E, wilo + (size_t)i * 2 * DI * E,
                                                  uz, ROWS, 2 * DI, E, 2 * DI);

    conv_silu16<<<ROWS / 16, 256, 0, stream>>>(uz, conv_w + i * DI * DCV, conv_b + i * DI, uc);

    dim3 g2(ROWS / 64, 1);
    gemm_bt<<<g2, 256, 0, stream>>>(uc, DI, xproj + (size_t)i * XDW * DI, DI,
                                    xdbl, XDW, ROWS, XDW, DI);

    scan_passA<<<BATCH * NCH, 256, 0, stream>>>(uc, xdbl, dtw + (size_t)i * DI * DRR, dtb + i * DI,
                                                A_log + (size_t)i * DI * DS, hloc, sumd);
    scan_passB<<<BATCH * (DI / 4), 64, 0, stream>>>(A_log + (size_t)i * DI * DS, hloc, sumd, hinit);
    scan_passC<<<BATCH * NCH, 256, 0, stream>>>(uc, xdbl, dtw + (size_t)i * DI * DRR, dtb + i * DI,
                                                A_log + (size_t)i * DI * DS, Dp + i * DI,
                                                uz, hinit, yhi, ylo);

    // h += y @ outproj^T   (M=ROWS, N=E=128, K=DI=256) — single column block (BN=128)
    dim3 g4(ROWS / 128, 1);
    mfma_gemm_lds<128, 1><<<g4, 256, 0, stream>>>(yhi, ylo,
                                                  wohi + (size_t)i * E * DI, wolo + (size_t)i * E * DI,
                                                  h, ROWS, E, DI, E);
  }

  ln_colsum<<<BATCH * 64, 256, 0, stream>>>(h, hn_g, hn_b, partial);
  fc_kernel<<<1, 256, 0, stream>>>(partial, fc_w, fc_b, out);
}

// Round 14
// 387.850 us; speedup vs baseline: 1.6315x; 1.0995x over previous
//
#include <hip/hip_runtime.h>
#include <hip/hip_bf16.h>
#include <math.h>

// Problem constants (CompactPointMamba: B=4, N=2048, E=128)
#define BATCH 4
#define NPTS  2048
#define L     4096      // 2*NPTS after concat of hilbert/trans orders
#define E     128
#define DI    256       // E*EXP
#define DS    16
#define DRR   8         // (E+15)//16
#define DCV   4
#define NBLK  2
#define NC    40
#define XDW   40        // DR + 2*DS
#define ROWS  (BATCH*L) // 16384
#define CH    16        // scan chunk length
#define NCH   256       // L / CH

typedef unsigned short u16;
typedef short short8 __attribute__((ext_vector_type(8)));
typedef float f32x4v __attribute__((ext_vector_type(4)));

// bf16 round-to-nearest-even helpers
__device__ __forceinline__ u16 f2bf(float x) {
  unsigned u = __float_as_uint(x);
  u = u + 0x7FFFu + ((u >> 16) & 1u);
  return (u16)(u >> 16);
}
__device__ __forceinline__ float bf2f(u16 h) {
  return __uint_as_float(((unsigned)h) << 16);
}
// fast softplus: ln(1+e^x) = ln2 * log2(1 + 2^(x*log2e))
__device__ __forceinline__ float softplusf(float x) {
  if (x > 20.f) return x;
  float t = __builtin_amdgcn_exp2f(x * 1.44269504f);
  return 0.69314718f * __builtin_amdgcn_logf(1.f + t);
}

// ---------------------------------------------------------------- embed + LN(block0) + split, row per wave
__global__ void embed_ln_split(const float* __restrict__ x,
                               const int* __restrict__ oh, const int* __restrict__ ot,
                               const float* __restrict__ pe_w, const float* __restrict__ pe_b,
                               const float* __restrict__ gamma, const float* __restrict__ beta,
                               const float* __restrict__ g, const float* __restrict__ bb,
                               float* __restrict__ h, u16* __restrict__ dhi, u16* __restrict__ dlo) {
  int wave = threadIdx.x >> 6;
  int lane = threadIdx.x & 63;
  int row = blockIdx.x * 4 + wave;        // b*L + n
  int n = row % L;
  int b = row / L;
  int gi = (n >= NPTS) ? 1 : 0;
  int nn = n - gi * NPTS;
  int src = gi ? ot[b * NPTS + nn] : oh[b * NPTS + nn];
  const float* xp = x + ((size_t)b * NPTS + src) * 3;
  float p0 = xp[0], p1 = xp[1], p2 = xp[2];
  int e0 = lane, e1 = lane + 64;
  float v0 = pe_b[e0] + p0 * pe_w[e0 * 3] + p1 * pe_w[e0 * 3 + 1] + p2 * pe_w[e0 * 3 + 2];
  float v1 = pe_b[e1] + p0 * pe_w[e1 * 3] + p1 * pe_w[e1 * 3 + 1] + p2 * pe_w[e1 * 3 + 2];
  v0 = v0 * gamma[gi * E + e0] + beta[gi * E + e0];
  v1 = v1 * gamma[gi * E + e1] + beta[gi * E + e1];
  size_t base = (size_t)row * E;
  h[base + e0] = v0;
  h[base + e1] = v1;
  // LN
  float s1 = v0 + v1, s2 = v0 * v0 + v1 * v1;
  #pragma unroll
  for (int off = 32; off > 0; off >>= 1) {
    s1 += __shfl_xor(s1, off);
    s2 += __shfl_xor(s2, off);
  }
  float m = s1 * (1.0f / E);
  float var = s2 * (1.0f / E) - m * m;
  float inv = rsqrtf(var + 1e-5f);
  float o0 = (v0 - m) * inv * g[e0] + bb[e0];
  float o1 = (v1 - m) * inv * g[e1] + bb[e1];
  u16 h0 = f2bf(o0), h1 = f2bf(o1);
  dhi[base + e0] = h0; dhi[base + e1] = h1;
  dlo[base + e0] = f2bf(o0 - bf2f(h0));
  dlo[base + e1] = f2bf(o1 - bf2f(h1));
}

// ---------------------------------------------------------------- split all weights (inproj + outw) in one dispatch
__global__ void split_all(const float* __restrict__ inproj, const float* __restrict__ outw,
                          u16* __restrict__ wihi, u16* __restrict__ wilo,
                          u16* __restrict__ wohi, u16* __restrict__ wolo) {
  const int n1 = NBLK * 2 * DI * E;
  const int n2 = NBLK * E * DI;
  int i = blockIdx.x * 256 + threadIdx.x;
  if (i < n1) {
    float v = inproj[i];
    u16 h = f2bf(v);
    wihi[i] = h; wilo[i] = f2bf(v - bf2f(h));
  } else if (i < n1 + n2) {
    int j = i - n1;
    float v = outw[j];
    u16 h = f2bf(v);
    wohi[j] = h; wolo[j] = f2bf(v - bf2f(h));
  }
}

// ---------------------------------------------------------------- layernorm -> bf16 hi/lo split (block 1)
__global__ void ln_split_kernel(const float* __restrict__ src, u16* __restrict__ dhi,
                                u16* __restrict__ dlo, const float* __restrict__ g,
                                const float* __restrict__ bb) {
  int wave = threadIdx.x >> 6;
  int lane = threadIdx.x & 63;
  int row = blockIdx.x * 4 + wave;
  const float* p = src + (size_t)row * E;
  float x0 = p[lane], x1 = p[lane + 64];
  float s1 = x0 + x1, s2 = x0 * x0 + x1 * x1;
  #pragma unroll
  for (int off = 32; off > 0; off >>= 1) {
    s1 += __shfl_xor(s1, off);
    s2 += __shfl_xor(s2, off);
  }
  float m = s1 * (1.0f / E);
  float v = s2 * (1.0f / E) - m * m;
  float inv = rsqrtf(v + 1e-5f);
  float v0 = (x0 - m) * inv * g[lane]      + bb[lane];
  float v1 = (x1 - m) * inv * g[lane + 64] + bb[lane + 64];
  size_t base = (size_t)row * E;
  u16 h0 = f2bf(v0), h1 = f2bf(v1);
  dhi[base + lane]      = h0;
  dhi[base + lane + 64] = h1;
  dlo[base + lane]      = f2bf(v0 - bf2f(h0));
  dlo[base + lane + 64] = f2bf(v1 - bf2f(h1));
}

// ---------------------------------------------------------------- LDS-staged split-bf16 MFMA GEMM
template<int BN, int ACC>
__global__ __launch_bounds__(256)
void mfma_gemm_lds(const u16* __restrict__ Ahi, const u16* __restrict__ Alo,
                   const u16* __restrict__ Bhi, const u16* __restrict__ Blo,
                   float* __restrict__ C, int M, int N, int K, int ldc) {
  constexpr int BM = 128, BK = 64, PITCH = 72;
  constexpr int MSUB = (BN == 128) ? 4 : 2;
  constexpr int NSUB = 4;
  __shared__ u16 sA[2][BM][PITCH];
  __shared__ u16 sB[2][BN][PITCH];
  int tid = threadIdx.x;
  int wave = tid >> 6, lane = tid & 63, quad = lane >> 4, l16 = lane & 15;
  int rowBase = blockIdx.x * BM, colBase = blockIdx.y * BN;
  int wrow = (BN == 128) ? (wave >> 1) * 64 : wave * 32;
  int wcol = (BN == 128) ? (wave & 1) * 64 : 0;
  f32x4v acc[MSUB][NSUB] = {};
  for (int k0 = 0; k0 < K; k0 += BK) {
    #pragma unroll
    for (int hl = 0; hl < 2; hl++) {
      const u16* srcA = hl ? Alo : Ahi;
      #pragma unroll
      for (int c = 0; c < BM * 8 / 256; c++) {
        int ch = c * 256 + tid;
        int row = ch >> 3, kc = ch & 7;
        float4 v = *(const float4*)(srcA + (size_t)(rowBase + row) * K + k0 + kc * 8);
        *(float4*)&sA[hl][row][kc * 8] = v;
      }
      const u16* srcB = hl ? Blo : Bhi;
      #pragma unroll
      for (int c = 0; c < BN * 8 / 256; c++) {
        int ch = c * 256 + tid;
        int row = ch >> 3, kc = ch & 7;
        float4 v = *(const float4*)(srcB + (size_t)(colBase + row) * K + k0 + kc * 8);
        *(float4*)&sB[hl][row][kc * 8] = v;
      }
    }
    __syncthreads();
    short8 afh[MSUB][2], afl[MSUB][2];
    #pragma unroll
    for (int i = 0; i < MSUB; i++)
      #pragma unroll
      for (int kf = 0; kf < 2; kf++) {
        afh[i][kf] = *(const short8*)&sA[0][wrow + i * 16 + l16][kf * 32 + quad * 8];
        afl[i][kf] = *(const short8*)&sA[1][wrow + i * 16 + l16][kf * 32 + quad * 8];
      }
    #pragma unroll
    for (int j = 0; j < NSUB; j++)
      #pragma unroll
      for (int kf = 0; kf < 2; kf++) {
        short8 bh = *(const short8*)&sB[0][wcol + j * 16 + l16][kf * 32 + quad * 8];
        short8 bl = *(const short8*)&sB[1][wcol + j * 16 + l16][kf * 32 + quad * 8];
        #pragma unroll
        for (int i = 0; i < MSUB; i++) {
          acc[i][j] = __builtin_amdgcn_mfma_f32_16x16x32_bf16(afh[i][kf], bh, acc[i][j], 0, 0, 0);
          acc[i][j] = __builtin_amdgcn_mfma_f32_16x16x32_bf16(afh[i][kf], bl, acc[i][j], 0, 0, 0);
          acc[i][j] = __builtin_amdgcn_mfma_f32_16x16x32_bf16(afl[i][kf], bh, acc[i][j], 0, 0, 0);
        }
      }
    __syncthreads();
  }
  int orow0 = rowBase + wrow + quad * 4;
  #pragma unroll
  for (int i = 0; i < MSUB; i++) {
    #pragma unroll
    for (int j = 0; j < NSUB; j++) {
      int cc = colBase + wcol + j * 16 + l16;
      #pragma unroll
      for (int r = 0; r < 4; r++) {
        size_t idx = (size_t)(orow0 + i * 16 + r) * ldc + cc;
        if (ACC) C[idx] += acc[i][j][r];
        else     C[idx] = acc[i][j][r];
      }
    }
  }
}

// ---------------------------------------------------------------- fused causal conv+silu+xproj
// 16 rows per block, 256 threads. Phase 1: thread d computes conv+silu for
// 16 rows -> LDS + global uc (coalesced). Phase 2: thread (og=tid/16, t=tid%16)
// computes xdbl outputs og, og+16, og+32(og<8) for row t. xw reads are wave-
// broadcast (16 same-og lanes share the address; 4 rows per wave-load).
__global__ __launch_bounds__(256)
void conv_xproj(const float* __restrict__ uz, const float* __restrict__ xw,
                const float* __restrict__ cw, const float* __restrict__ cb,
                float* __restrict__ uc, float* __restrict__ xdbl) {
  __shared__ float uc_sh[16][DI + 4];
  int d = threadIdx.x;
  int r0 = blockIdx.x * 16;
  int b = r0 / L;
  int t0 = r0 % L;
  float w0 = cw[d * DCV], w1 = cw[d * DCV + 1], w2 = cw[d * DCV + 2], w3 = cw[d * DCV + 3];
  float bias = cb[d];
  const float* up = uz + ((size_t)b * L + t0) * (2 * DI) + d;
  float p0 = 0.f, p1 = 0.f, p2 = 0.f;
  if (t0 > 0) {                   // halo (t0==0 only at batch start -> zero pad)
    p0 = up[-3 * (2 * DI)];
    p1 = up[-2 * (2 * DI)];
    p2 = up[-1 * (2 * DI)];
  }
  #pragma unroll
  for (int j = 0; j < 16; j++) {
    float cur = up[(size_t)j * (2 * DI)];
    float a = bias + w0 * p0 + w1 * p1 + w2 * p2 + w3 * cur;
    float s = a / (1.f + __expf(-a));
    uc_sh[j][d] = s;
    uc[((size_t)r0 + j) * DI + d] = s;
    p0 = p1; p1 = p2; p2 = cur;
  }
  __syncthreads();
  int og = threadIdx.x >> 4, t = threadIdx.x & 15;
  const float* x0 = xw + (size_t)og * DI;
  const float* x1 = xw + (size_t)(og + 16) * DI;
  const float* x2 = xw + (size_t)(og + 32) * DI;
  const float* ucrow = uc_sh[t];
  float a0 = 0.f, a1 = 0.f, a2 = 0.f;
  bool has2 = og < 8;
  #pragma unroll 8
  for (int k = 0; k < DI; k += 4) {
    float4 u4 = *(const float4*)&ucrow[k];
    float4 pa = *(const float4*)&x0[k];
    float4 pb = *(const float4*)&x1[k];
    a0 += u4.x * pa.x + u4.y * pa.y + u4.z * pa.z + u4.w * pa.w;
    a1 += u4.x * pb.x + u4.y * pb.y + u4.z * pb.z + u4.w * pb.w;
    if (has2) {
      float4 pc = *(const float4*)&x2[k];
      a2 += u4.x * pc.x + u4.y * pc.y + u4.z * pc.z + u4.w * pc.w;
    }
  }
  size_t rb = (size_t)(r0 + t) * XDW;
  xdbl[rb + og] = a0;
  xdbl[rb + og + 16] = a1;
  if (has2) xdbl[rb + og + 32] = a2;
}

// ---------------------------------------------------------------- scan pass A (dtproj+softplus fused)
// hloc layout: [b][c][d][s]  (coalesced for threads=d); sumd: [b][c][d]
__global__ __launch_bounds__(256, 4)
void scan_passA(const float* __restrict__ uc, const float* __restrict__ xdbl,
                const float* __restrict__ dtw, const float* __restrict__ dtb,
                const float* __restrict__ A_log,
                float* __restrict__ hloc, float* __restrict__ sumd) {
  int b = blockIdx.x / NCH, c = blockIdx.x % NCH;
  int d = threadIdx.x;
  __shared__ float Bsh[CH][DS];
  __shared__ float Dsh[CH][DRR];
  {
    int i = threadIdx.x;
    int t0 = i >> 4, s = i & 15;
    size_t rb = ((size_t)b * L + c * CH + t0) * XDW;
    Bsh[t0][s] = xdbl[rb + DRR + s];
    if (i < CH * DRR) {
      int td = i >> 3, q = i & 7;
      Dsh[td][q] = xdbl[((size_t)b * L + c * CH + td) * XDW + q];
    }
  }
  // prefetch global while LDS staging is in flight
  float ut[CH];
  const float* uc_p = uc + ((size_t)b * L + c * CH) * DI + d;
  #pragma unroll
  for (int t0 = 0; t0 < CH; t0++) ut[t0] = uc_p[(size_t)t0 * DI];
  float Av[DS];
  #pragma unroll
  for (int s = 0; s < DS; s++) Av[s] = -__expf(A_log[d * DS + s]);
  float4 w0 = *(const float4*)(dtw + d * DRR);
  float4 w1 = *(const float4*)(dtw + d * DRR + 4);
  float bias = dtb[d];
  __syncthreads();
  float dl[CH];
  float sd = 0.f;
  #pragma unroll
  for (int t0 = 0; t0 < CH; t0++) {
    float4 D0 = *(const float4*)&Dsh[t0][0];
    float4 D1 = *(const float4*)&Dsh[t0][4];
    float v = bias + D0.x * w0.x + D0.y * w0.y + D0.z * w0.z + D0.w * w0.w
                   + D1.x * w1.x + D1.y * w1.y + D1.z * w1.z + D1.w * w1.w;
    dl[t0] = softplusf(v);
    sd += dl[t0];
  }
  float st[DS] = {};
  #pragma unroll
  for (int t0 = 0; t0 < CH; t0++) {
    float du = dl[t0] * ut[t0];
    float4 B0 = *(const float4*)&Bsh[t0][0];
    float4 B1 = *(const float4*)&Bsh[t0][4];
    float4 B2 = *(const float4*)&Bsh[t0][8];
    float4 B3 = *(const float4*)&Bsh[t0][12];
    float Bv[DS] = {B0.x, B0.y, B0.z, B0.w, B1.x, B1.y, B1.z, B1.w,
                    B2.x, B2.y, B2.z, B2.w, B3.x, B3.y, B3.z, B3.w};
    #pragma unroll
    for (int s = 0; s < DS; s++) {
      float a = __expf(dl[t0] * Av[s]);
      st[s] = a * st[s] + du * Bv[s];
    }
  }
  size_t base = (((size_t)b * NCH + c) * DI + d) * DS;
  *(float4*)&hloc[base + 0]  = float4{st[0], st[1], st[2], st[3]};
  *(float4*)&hloc[base + 4]  = float4{st[4], st[5], st[6], st[7]};
  *(float4*)&hloc[base + 8]  = float4{st[8], st[9], st[10], st[11]};
  *(float4*)&hloc[base + 12] = float4{st[12], st[13], st[14], st[15]};
  sumd[((size_t)b * NCH + c) * DI + d] = sd;
}

// ---------------------------------------------------------------- scan pass B: coalesced serial scan, depth-8 prefetch
#define PB_G 8
__global__ __launch_bounds__(64)
void scan_passB(const float* __restrict__ A_log, const float* __restrict__ hloc,
                const float* __restrict__ sumd, float* __restrict__ hinit) {
  int tid = threadIdx.x;
  int dgroup = blockIdx.x % (DI / 4);
  int b = blockIdx.x / (DI / 4);
  int d = dgroup * 4 + (tid >> 4);
  int s = tid & 15;
  float Av = -__expf(A_log[d * DS + s]);
  size_t off = (size_t)b * NCH * DI * DS + dgroup * 64 + tid;
  size_t soff = (size_t)b * NCH * DI + d;
  const size_t HST = (size_t)DI * DS;
  float bv[PB_G], sd[PB_G], bvn[PB_G], sdn[PB_G];
  #pragma unroll
  for (int j = 0; j < PB_G; j++) {
    bv[j] = hloc[off + j * HST];
    sd[j] = sumd[soff + j * DI];
  }
  float X = 0.f;
  for (int g = 0; g < NCH / PB_G; g++) {
    if (g + 1 < NCH / PB_G) {
      #pragma unroll
      for (int j = 0; j < PB_G; j++) {
        bvn[j] = hloc[off + (j + PB_G) * HST];
        sdn[j] = sumd[soff + (j + PB_G) * DI];
      }
    }
    #pragma unroll
    for (int j = 0; j < PB_G; j++) {
      float a = __expf(Av * sd[j]);
      hinit[off + j * HST] = X;
      X = a * X + bv[j];
    }
    #pragma unroll
    for (int j = 0; j < PB_G; j++) { bv[j] = bvn[j]; sd[j] = sdn[j]; }
    off += PB_G * HST;
    soff += PB_G * DI;
  }
}

// ---------------------------------------------------------------- scan pass C (dtproj fused; y -> bf16 hi/lo)
__global__ __launch_bounds__(256, 4)
void scan_passC(const float* __restrict__ uc, const float* __restrict__ xdbl,
                const float* __restrict__ dtw, const float* __restrict__ dtb,
                const float* __restrict__ A_log, const float* __restrict__ Dp,
                const float* __restrict__ uz, const float* __restrict__ hinit,
                u16* __restrict__ yhi, u16* __restrict__ ylo) {
  int b = blockIdx.x / NCH, c = blockIdx.x % NCH;
  int d = threadIdx.x;
  __shared__ float Bsh[CH][DS];
  __shared__ float Csh[CH][DS];
  __shared__ float Dsh[CH][DRR];
  {
    int i = threadIdx.x;
    int t0 = i >> 4, s = i & 15;
    size_t rb = ((size_t)b * L + c * CH + t0) * XDW;
    Bsh[t0][s] = xdbl[rb + DRR + s];
    Csh[t0][s] = xdbl[rb + DRR + DS + s];
    if (i < CH * DRR) {
      int td = i >> 3, q = i & 7;
      Dsh[td][q] = xdbl[((size_t)b * L + c * CH + td) * XDW + q];
    }
  }
  // prefetch
  float ut[CH];
  const float* uc_p = uc + ((size_t)b * L + c * CH) * DI + d;
  #pragma unroll
  for (int t0 = 0; t0 < CH; t0++) ut[t0] = uc_p[(size_t)t0 * DI];
  float st[DS];
  size_t hbase = (((size_t)b * NCH + c) * DI + d) * DS;
  {
    float4 h0 = *(const float4*)&hinit[hbase + 0];
    float4 h1 = *(const float4*)&hinit[hbase + 4];
    float4 h2 = *(const float4*)&hinit[hbase + 8];
    float4 h3 = *(const float4*)&hinit[hbase + 12];
    st[0]=h0.x; st[1]=h0.y; st[2]=h0.z; st[3]=h0.w;
    st[4]=h1.x; st[5]=h1.y; st[6]=h1.z; st[7]=h1.w;
    st[8]=h2.x; st[9]=h2.y; st[10]=h2.z; st[11]=h2.w;
    st[12]=h3.x; st[13]=h3.y; st[14]=h3.z; st[15]=h3.w;
  }
  float Av[DS];
  #pragma unroll
  for (int s = 0; s < DS; s++) Av[s] = -__expf(A_log[d * DS + s]);
  float4 w0 = *(const float4*)(dtw + d * DRR);
  float4 w1 = *(const float4*)(dtw + d * DRR + 4);
  float bias = dtb[d];
  float Dv = Dp[d];
  const float* z_p = uz + ((size_t)b * L + c * CH) * (2 * DI) + DI + d;
  size_t ybase = ((size_t)b * L + c * CH) * DI + d;
  __syncthreads();
  float dl[CH];
  #pragma unroll
  for (int t0 = 0; t0 < CH; t0++) {
    float4 D0 = *(const float4*)&Dsh[t0][0];
    float4 D1 = *(const float4*)&Dsh[t0][4];
    float v = bias + D0.x * w0.x + D0.y * w0.y + D0.z * w0.z + D0.w * w0.w
                   + D1.x * w1.x + D1.y * w1.y + D1.z * w1.z + D1.w * w1.w;
    dl[t0] = softplusf(v);
  }
  float znext = z_p[0];
  #pragma unroll
  for (int t0 = 0; t0 < CH; t0++) {
    float zz = znext;
    if (t0 < CH - 1) znext = z_p[(size_t)(t0 + 1) * (2 * DI)];
    float du = dl[t0] * ut[t0];
    float acc = Dv * ut[t0];
    float4 B0 = *(const float4*)&Bsh[t0][0];
    float4 B1 = *(const float4*)&Bsh[t0][4];
    float4 B2 = *(const float4*)&Bsh[t0][8];
    float4 B3 = *(const float4*)&Bsh[t0][12];
    float4 C0 = *(const float4*)&Csh[t0][0];
    float4 C1 = *(const float4*)&Csh[t0][4];
    float4 C2 = *(const float4*)&Csh[t0][8];
    float4 C3 = *(const float4*)&Csh[t0][12];
    float Bv[DS] = {B0.x, B0.y, B0.z, B0.w, B1.x, B1.y, B1.z, B1.w,
                    B2.x, B2.y, B2.z, B2.w, B3.x, B3.y, B3.z, B3.w};
    float Cv[DS] = {C0.x, C0.y, C0.z, C0.w, C1.x, C1.y, C1.z, C1.w,
                    C2.x, C2.y, C2.z, C2.w, C3.x, C3.y, C3.z, C3.w};
    #pragma unroll
    for (int s = 0; s < DS; s++) {
      float a = __expf(dl[t0] * Av[s]);
      st[s] = a * st[s] + du * Bv[s];
      acc += st[s] * Cv[s];
    }
    float v = acc * (zz / (1.f + __expf(-zz)));
    u16 hh = f2bf(v);
    yhi[ybase + (size_t)t0 * DI] = hh;
    ylo[ybase + (size_t)t0 * DI] = f2bf(v - bf2f(hh));
  }
}

// ---------------------------------------------------------------- final LN + column-sum partials
__global__ void ln_colsum(const float* __restrict__ h, const float* __restrict__ g,
                          const float* __restrict__ bb, float* __restrict__ partial) {
  int blk = blockIdx.x;
  int b = blk / 64, grp = blk % 64;
  int wave = threadIdx.x >> 6, lane = threadIdx.x & 63;
  float a0 = 0.f, a1 = 0.f;
  float g0 = g[lane], g1 = g[lane + 64], b0 = bb[lane], b1 = bb[lane + 64];
  for (int j = 0; j < 16; j++) {
    int row = b * L + grp * 64 + wave * 16 + j;
    const float* p = h + (size_t)row * E;
    float x0 = p[lane], x1 = p[lane + 64];
    float s1 = x0 + x1, s2 = x0 * x0 + x1 * x1;
    #pragma unroll
    for (int off = 32; off > 0; off >>= 1) {
      s1 += __shfl_xor(s1, off);
      s2 += __shfl_xor(s2, off);
    }
    float m = s1 * (1.0f / E);
    float var = s2 * (1.0f / E) - m * m;
    float inv = rsqrtf(var + 1e-5f);
    a0 += (x0 - m) * inv * g0 + b0;
    a1 += (x1 - m) * inv * g1 + b1;
  }
  __shared__ float red[4][128];
  red[wave][lane] = a0;
  red[wave][lane + 64] = a1;
  __syncthreads();
  if (wave == 0) {
    #pragma unroll
    for (int half = 0; half < 2; half++) {
      int e = lane + half * 64;
      float s = red[0][e] + red[1][e] + red[2][e] + red[3][e];
      partial[(size_t)blk * E + e] = s;
    }
  }
}

// ---------------------------------------------------------------- final FC (reduce partials + project)
__global__ void fc_kernel(const float* __restrict__ partial, const float* __restrict__ fcw,
                          const float* __restrict__ fcb, float* __restrict__ out) {
  __shared__ float hm[BATCH * E];
  for (int idx = threadIdx.x; idx < BATCH * E; idx += 256) {
    int b = idx >> 7, e = idx & 127;
    float s = 0.f;
    for (int g2 = 0; g2 < 64; g2++) s += partial[(size_t)(b * 64 + g2) * E + e];
    hm[idx] = s;
  }
  __syncthreads();
  int i = threadIdx.x;
  if (i < BATCH * NC) {
    int b = i / NC, o = i % NC;
    float acc = 0.f;
    for (int e = 0; e < E; e++) acc += hm[b * E + e] * fcw[o * E + e];
    out[i] = acc * (1.f / L) + fcb[o];
  }
}

// ---------------------------------------------------------------- launch
extern "C" void kernel_launch(void* const* d_in, const int* in_sizes, int n_in,
                              void* d_out, int out_size, void* d_ws, size_t ws_size,
                              hipStream_t stream) {
  const float* x      = (const float*)d_in[0];
  const int*   oh     = (const int*)d_in[1];
  const int*   ot     = (const int*)d_in[2];
  const float* pe_w   = (const float*)d_in[3];
  const float* pe_b   = (const float*)d_in[4];
  const float* gamma  = (const float*)d_in[5];
  const float* beta   = (const float*)d_in[6];
  const float* ln_g   = (const float*)d_in[7];
  const float* ln_b   = (const float*)d_in[8];
  const float* inproj = (const float*)d_in[9];
  const float* conv_w = (const float*)d_in[10];
  const float* conv_b = (const float*)d_in[11];
  const float* xproj  = (const float*)d_in[12];
  const float* dtw    = (const float*)d_in[13];
  const float* dtb    = (const float*)d_in[14];
  const float* A_log  = (const float*)d_in[15];
  const float* Dp     = (const float*)d_in[16];
  const float* outw   = (const float*)d_in[17];
  const float* hn_g   = (const float*)d_in[18];
  const float* hn_b   = (const float*)d_in[19];
  const float* fc_w   = (const float*)d_in[20];
  const float* fc_b   = (const float*)d_in[21];
  float* out = (float*)d_out;

  char* ws = (char*)d_ws;
  size_t off = 0;
  auto alloc = [&](size_t bytes) { size_t o = off; off += (bytes + 255) & ~(size_t)255; return o; };
  float* h     = (float*)(ws + alloc((size_t)ROWS * E * 4));              // 8 MB
  u16*   xnhi  = (u16*)  (ws + alloc((size_t)ROWS * E * 2));              // 4 MB
  u16*   xnlo  = (u16*)  (ws + alloc((size_t)ROWS * E * 2));              // 4 MB
  float* uz    = (float*)(ws + alloc((size_t)ROWS * 2 * DI * 4));         // 32 MB
  float* uc    = (float*)(ws + alloc((size_t)ROWS * DI * 4));             // 16 MB
  float* xdbl  = (float*)(ws + alloc((size_t)ROWS * XDW * 4));            // 2.6 MB
  u16*   yhi   = (u16*)  (ws + alloc((size_t)ROWS * DI * 2));             // 8 MB
  u16*   ylo   = (u16*)  (ws + alloc((size_t)ROWS * DI * 2));             // 8 MB
  float* hloc  = (float*)(ws + alloc((size_t)BATCH * NCH * DI * DS * 4)); // 16.8 MB
  float* sumd  = (float*)(ws + alloc((size_t)BATCH * NCH * DI * 4));      // 1 MB
  u16*   wihi  = (u16*)  (ws + alloc((size_t)NBLK * 2 * DI * E * 2));     // 256 KB
  u16*   wilo  = (u16*)  (ws + alloc((size_t)NBLK * 2 * DI * E * 2));     // 256 KB
  u16*   wohi  = (u16*)  (ws + alloc((size_t)NBLK * E * DI * 2));         // 128 KB
  u16*   wolo  = (u16*)  (ws + alloc((size_t)NBLK * E * DI * 2));         // 128 KB
  float* partial = (float*)(ws + alloc((size_t)BATCH * 64 * E * 4));      // 128 KB
  float* hinit = hloc;    // passB: same-thread read-before-write per element

  embed_ln_split<<<ROWS / 4, 256, 0, stream>>>(x, oh, ot, pe_w, pe_b, gamma, beta,
                                               ln_g, ln_b, h, xnhi, xnlo);
  split_all<<<(NBLK * 2 * DI * E + NBLK * E * DI + 255) / 256, 256, 0, stream>>>(
      inproj, outw, wihi, wilo, wohi, wolo);

  for (int i = 0; i < NBLK; i++) {
    if (i > 0)
      ln_split_kernel<<<ROWS / 4, 256, 0, stream>>>(h, xnhi, xnlo, ln_g + i * E, ln_b + i * E);

    // uz = xn @ inproj^T   (M=ROWS, N=2*DI=512, K=E=128)
    dim3 g1(ROWS / 128, (2 * DI) / 128);
    mfma_gemm_lds<128, 0><<<g1, 256, 0, stream>>>(xnhi, xnlo,
                                                  wihi + (size_t)i * 2 * DI * E, wilo + (size_t)i * 2 * DI * E,
                                                  uz, ROWS, 2 * DI, E, 2 * DI);

    // fused conv+silu+xproj (writes uc and xdbl)
    conv_xproj<<<ROWS / 16, 256, 0, stream>>>(uz, xproj + (size_t)i * XDW * DI,
                                              conv_w + i * DI * DCV, conv_b + i * DI,
                                              uc, xdbl);

    scan_passA<<<BATCH * NCH, 256, 0, stream>>>(uc, xdbl, dtw + (size_t)i * DI * DRR, dtb + i * DI,
                                                A_log + (size_t)i * DI * DS, hloc, sumd);
    scan_passB<<<BATCH * (DI / 4), 64, 0, stream>>>(A_log + (size_t)i * DI * DS, hloc, sumd, hinit);
    scan_passC<<<BATCH * NCH, 256, 0, stream>>>(uc, xdbl, dtw + (size_t)i * DI * DRR, dtb + i * DI,
                                                A_log + (size_t)i * DI * DS, Dp + i * DI,
                                                uz, hinit, yhi, ylo);

    // h += y @ outproj^T   (M=ROWS, N=E=128, K=DI=256) — R11 config: grid (128, 2)
    dim3 g4(ROWS / 128, E / 64);
    mfma_gemm_lds<64, 1><<<g4, 256, 0, stream>>>(yhi, ylo,
                                                 wohi + (size_t)i * E * DI, wolo + (size_t)i * E * DI,
                                                 h, ROWS, E, DI, E);
  }

  ln_colsum<<<BATCH * 64, 256, 0, stream>>>(h, hn_g, hn_b, partial);
  fc_kernel<<<1, 256, 0, stream>>>(partial, fc_w, fc_b, out);
}

// Round 15
// 367.949 us; speedup vs baseline: 1.7197x; 1.0541x over previous
//
#include <hip/hip_runtime.h>
#include <hip/hip_bf16.h>
#include <math.h>

// Problem constants (CompactPointMamba: B=4, N=2048, E=128)
#define BATCH 4
#define NPTS  2048
#define L     4096      // 2*NPTS after concat of hilbert/trans orders
#define E     128
#define DI    256       // E*EXP
#define DS    16
#define DRR   8         // (E+15)//16
#define DCV   4
#define NBLK  2
#define NC    40
#define XDW   40        // DR + 2*DS
#define ROWS  (BATCH*L) // 16384
#define CH    16        // scan chunk length
#define NCH   256       // L / CH

typedef unsigned short u16;
typedef short short8 __attribute__((ext_vector_type(8)));
typedef float f32x4v __attribute__((ext_vector_type(4)));

// bf16 round-to-nearest-even helpers
__device__ __forceinline__ u16 f2bf(float x) {
  unsigned u = __float_as_uint(x);
  u = u + 0x7FFFu + ((u >> 16) & 1u);
  return (u16)(u >> 16);
}
__device__ __forceinline__ float bf2f(u16 h) {
  return __uint_as_float(((unsigned)h) << 16);
}
// fast softplus: ln(1+e^x) = ln2 * log2(1 + 2^(x*log2e))
__device__ __forceinline__ float softplusf(float x) {
  if (x > 20.f) return x;
  float t = __builtin_amdgcn_exp2f(x * 1.44269504f);
  return 0.69314718f * __builtin_amdgcn_logf(1.f + t);
}

// ---------------------------------------------------------------- embed + LN(block0) + split, row per wave
__global__ void embed_ln_split(const float* __restrict__ x,
                               const int* __restrict__ oh, const int* __restrict__ ot,
                               const float* __restrict__ pe_w, const float* __restrict__ pe_b,
                               const float* __restrict__ gamma, const float* __restrict__ beta,
                               const float* __restrict__ g, const float* __restrict__ bb,
                               float* __restrict__ h, u16* __restrict__ dhi, u16* __restrict__ dlo) {
  int wave = threadIdx.x >> 6;
  int lane = threadIdx.x & 63;
  int row = blockIdx.x * 4 + wave;        // b*L + n
  int n = row % L;
  int b = row / L;
  int gi = (n >= NPTS) ? 1 : 0;
  int nn = n - gi * NPTS;
  int src = gi ? ot[b * NPTS + nn] : oh[b * NPTS + nn];
  const float* xp = x + ((size_t)b * NPTS + src) * 3;
  float p0 = xp[0], p1 = xp[1], p2 = xp[2];
  int e0 = lane, e1 = lane + 64;
  float v0 = pe_b[e0] + p0 * pe_w[e0 * 3] + p1 * pe_w[e0 * 3 + 1] + p2 * pe_w[e0 * 3 + 2];
  float v1 = pe_b[e1] + p0 * pe_w[e1 * 3] + p1 * pe_w[e1 * 3 + 1] + p2 * pe_w[e1 * 3 + 2];
  v0 = v0 * gamma[gi * E + e0] + beta[gi * E + e0];
  v1 = v1 * gamma[gi * E + e1] + beta[gi * E + e1];
  size_t base = (size_t)row * E;
  h[base + e0] = v0;
  h[base + e1] = v1;
  // LN
  float s1 = v0 + v1, s2 = v0 * v0 + v1 * v1;
  #pragma unroll
  for (int off = 32; off > 0; off >>= 1) {
    s1 += __shfl_xor(s1, off);
    s2 += __shfl_xor(s2, off);
  }
  float m = s1 * (1.0f / E);
  float var = s2 * (1.0f / E) - m * m;
  float inv = rsqrtf(var + 1e-5f);
  float o0 = (v0 - m) * inv * g[e0] + bb[e0];
  float o1 = (v1 - m) * inv * g[e1] + bb[e1];
  u16 h0 = f2bf(o0), h1 = f2bf(o1);
  dhi[base + e0] = h0; dhi[base + e1] = h1;
  dlo[base + e0] = f2bf(o0 - bf2f(h0));
  dlo[base + e1] = f2bf(o1 - bf2f(h1));
}

// ---------------------------------------------------------------- split all weights (inproj + outw) in one dispatch
__global__ void split_all(const float* __restrict__ inproj, const float* __restrict__ outw,
                          u16* __restrict__ wihi, u16* __restrict__ wilo,
                          u16* __restrict__ wohi, u16* __restrict__ wolo) {
  const int n1 = NBLK * 2 * DI * E;
  const int n2 = NBLK * E * DI;
  int i = blockIdx.x * 256 + threadIdx.x;
  if (i < n1) {
    float v = inproj[i];
    u16 h = f2bf(v);
    wihi[i] = h; wilo[i] = f2bf(v - bf2f(h));
  } else if (i < n1 + n2) {
    int j = i - n1;
    float v = outw[j];
    u16 h = f2bf(v);
    wohi[j] = h; wolo[j] = f2bf(v - bf2f(h));
  }
}

// ---------------------------------------------------------------- LDS-staged split-bf16 MFMA GEMM (inproj)
template<int BN, int ACC>
__global__ __launch_bounds__(256)
void mfma_gemm_lds(const u16* __restrict__ Ahi, const u16* __restrict__ Alo,
                   const u16* __restrict__ Bhi, const u16* __restrict__ Blo,
                   float* __restrict__ C, int M, int N, int K, int ldc) {
  constexpr int BM = 128, BK = 64, PITCH = 72;
  constexpr int MSUB = (BN == 128) ? 4 : 2;
  constexpr int NSUB = 4;
  __shared__ u16 sA[2][BM][PITCH];
  __shared__ u16 sB[2][BN][PITCH];
  int tid = threadIdx.x;
  int wave = tid >> 6, lane = tid & 63, quad = lane >> 4, l16 = lane & 15;
  int rowBase = blockIdx.x * BM, colBase = blockIdx.y * BN;
  int wrow = (BN == 128) ? (wave >> 1) * 64 : wave * 32;
  int wcol = (BN == 128) ? (wave & 1) * 64 : 0;
  f32x4v acc[MSUB][NSUB] = {};
  for (int k0 = 0; k0 < K; k0 += BK) {
    #pragma unroll
    for (int hl = 0; hl < 2; hl++) {
      const u16* srcA = hl ? Alo : Ahi;
      #pragma unroll
      for (int c = 0; c < BM * 8 / 256; c++) {
        int ch = c * 256 + tid;
        int row = ch >> 3, kc = ch & 7;
        float4 v = *(const float4*)(srcA + (size_t)(rowBase + row) * K + k0 + kc * 8);
        *(float4*)&sA[hl][row][kc * 8] = v;
      }
      const u16* srcB = hl ? Blo : Bhi;
      #pragma unroll
      for (int c = 0; c < BN * 8 / 256; c++) {
        int ch = c * 256 + tid;
        int row = ch >> 3, kc = ch & 7;
        float4 v = *(const float4*)(srcB + (size_t)(colBase + row) * K + k0 + kc * 8);
        *(float4*)&sB[hl][row][kc * 8] = v;
      }
    }
    __syncthreads();
    short8 afh[MSUB][2], afl[MSUB][2];
    #pragma unroll
    for (int i = 0; i < MSUB; i++)
      #pragma unroll
      for (int kf = 0; kf < 2; kf++) {
        afh[i][kf] = *(const short8*)&sA[0][wrow + i * 16 + l16][kf * 32 + quad * 8];
        afl[i][kf] = *(const short8*)&sA[1][wrow + i * 16 + l16][kf * 32 + quad * 8];
      }
    #pragma unroll
    for (int j = 0; j < NSUB; j++)
      #pragma unroll
      for (int kf = 0; kf < 2; kf++) {
        short8 bh = *(const short8*)&sB[0][wcol + j * 16 + l16][kf * 32 + quad * 8];
        short8 bl = *(const short8*)&sB[1][wcol + j * 16 + l16][kf * 32 + quad * 8];
        #pragma unroll
        for (int i = 0; i < MSUB; i++) {
          acc[i][j] = __builtin_amdgcn_mfma_f32_16x16x32_bf16(afh[i][kf], bh, acc[i][j], 0, 0, 0);
          acc[i][j] = __builtin_amdgcn_mfma_f32_16x16x32_bf16(afh[i][kf], bl, acc[i][j], 0, 0, 0);
          acc[i][j] = __builtin_amdgcn_mfma_f32_16x16x32_bf16(afl[i][kf], bh, acc[i][j], 0, 0, 0);
        }
      }
    __syncthreads();
  }
  int orow0 = rowBase + wrow + quad * 4;
  #pragma unroll
  for (int i = 0; i < MSUB; i++) {
    #pragma unroll
    for (int j = 0; j < NSUB; j++) {
      int cc = colBase + wcol + j * 16 + l16;
      #pragma unroll
      for (int r = 0; r < 4; r++) {
        size_t idx = (size_t)(orow0 + i * 16 + r) * ldc + cc;
        if (ACC) C[idx] += acc[i][j][r];
        else     C[idx] = acc[i][j][r];
      }
    }
  }
}

// ---------------------------------------------------------------- outproj + residual + LN fused
// BM=64, BN=E=128, K=DI=256. grid: ROWS/64 = 256 blocks x 256 threads.
// VARIANT 0: h += y@W^T (written), LN -> bf16 hi/lo split (next block's input).
// VARIANT 1: h += y@W^T (NOT written), LN -> per-block colsum partial.
template<int VARIANT>
__global__ __launch_bounds__(256)
void outproj_fused(const u16* __restrict__ Ahi, const u16* __restrict__ Alo,
                   const u16* __restrict__ Bhi, const u16* __restrict__ Blo,
                   float* __restrict__ h, const float* __restrict__ g,
                   const float* __restrict__ bb, u16* __restrict__ dhi,
                   u16* __restrict__ dlo, float* __restrict__ partial) {
  constexpr int BM = 64, BN = 128, BK = 64, PITCH = 72, HP = 132;
  __shared__ __align__(16) char smem_raw[2 * BM * PITCH * 2 + 2 * BN * PITCH * 2]; // 55296 B
  u16* sA = (u16*)smem_raw;                 // [2][BM][PITCH]
  u16* sB = sA + 2 * BM * PITCH;            // [2][BN][PITCH]
  int tid = threadIdx.x;
  int wave = tid >> 6, lane = tid & 63, quad = lane >> 4, l16 = lane & 15;
  int r0 = blockIdx.x * BM;
  int wrow = wave * 16;
  f32x4v acc[8] = {};
  for (int k0 = 0; k0 < DI; k0 += BK) {
    #pragma unroll
    for (int hl = 0; hl < 2; hl++) {
      const u16* srcA = hl ? Alo : Ahi;
      #pragma unroll
      for (int c = 0; c < 2; c++) {          // BM*8/256
        int ch = c * 256 + tid;
        int row = ch >> 3, kc = ch & 7;
        float4 v = *(const float4*)(srcA + (size_t)(r0 + row) * DI + k0 + kc * 8);
        *(float4*)&sA[(hl * BM + row) * PITCH + kc * 8] = v;
      }
      const u16* srcB = hl ? Blo : Bhi;
      #pragma unroll
      for (int c = 0; c < 4; c++) {          // BN*8/256
        int ch = c * 256 + tid;
        int row = ch >> 3, kc = ch & 7;
        float4 v = *(const float4*)(srcB + (size_t)row * DI + k0 + kc * 8);
        *(float4*)&sB[(hl * BN + row) * PITCH + kc * 8] = v;
      }
    }
    __syncthreads();
    short8 ah[2], al[2];
    #pragma unroll
    for (int kf = 0; kf < 2; kf++) {
      ah[kf] = *(const short8*)&sA[(0 * BM + wrow + l16) * PITCH + kf * 32 + quad * 8];
      al[kf] = *(const short8*)&sA[(1 * BM + wrow + l16) * PITCH + kf * 32 + quad * 8];
    }
    #pragma unroll
    for (int j = 0; j < 8; j++)
      #pragma unroll
      for (int kf = 0; kf < 2; kf++) {
        short8 bh = *(const short8*)&sB[(0 * BN + j * 16 + l16) * PITCH + kf * 32 + quad * 8];
        short8 bl = *(const short8*)&sB[(1 * BN + j * 16 + l16) * PITCH + kf * 32 + quad * 8];
        acc[j] = __builtin_amdgcn_mfma_f32_16x16x32_bf16(ah[kf], bh, acc[j], 0, 0, 0);
        acc[j] = __builtin_amdgcn_mfma_f32_16x16x32_bf16(ah[kf], bl, acc[j], 0, 0, 0);
        acc[j] = __builtin_amdgcn_mfma_f32_16x16x32_bf16(al[kf], bh, acc[j], 0, 0, 0);
      }
    __syncthreads();   // all LDS reads done -> safe to reuse smem for epilogue
  }
  // epilogue: residual add, stage rows to LDS (reusing smem)
  float* hsm = (float*)smem_raw;            // [64][HP] = 33792 B
  float* red = hsm + BM * HP;               // [4][128] = 2048 B  (total 35840 <= 55296)
  int orow = wrow + quad * 4;
  #pragma unroll
  for (int j = 0; j < 8; j++) {
    int cc = j * 16 + l16;
    #pragma unroll
    for (int r = 0; r < 4; r++) {
      float v = h[(size_t)(r0 + orow + r) * E + cc] + acc[j][r];
      hsm[(orow + r) * HP + cc] = v;
      if (VARIANT == 0) h[(size_t)(r0 + orow + r) * E + cc] = v;
    }
  }
  __syncthreads();
  // LN per row: wave w handles rows wrow..wrow+15; lane covers cols lane, lane+64
  float g0 = g[lane], g1 = g[lane + 64], b0 = bb[lane], b1 = bb[lane + 64];
  float a0 = 0.f, a1 = 0.f;
  for (int jj = 0; jj < 16; jj++) {
    int row = wrow + jj;
    float x0 = hsm[row * HP + lane], x1 = hsm[row * HP + lane + 64];
    float s1 = x0 + x1, s2 = x0 * x0 + x1 * x1;
    #pragma unroll
    for (int off = 32; off > 0; off >>= 1) {
      s1 += __shfl_xor(s1, off);
      s2 += __shfl_xor(s2, off);
    }
    float m = s1 * (1.0f / E);
    float var = s2 * (1.0f / E) - m * m;
    float inv = rsqrtf(var + 1e-5f);
    float o0 = (x0 - m) * inv * g0 + b0;
    float o1 = (x1 - m) * inv * g1 + b1;
    if (VARIANT == 0) {
      size_t base = (size_t)(r0 + row) * E;
      u16 h0 = f2bf(o0), h1 = f2bf(o1);
      dhi[base + lane]      = h0;
      dhi[base + lane + 64] = h1;
      dlo[base + lane]      = f2bf(o0 - bf2f(h0));
      dlo[base + lane + 64] = f2bf(o1 - bf2f(h1));
    } else {
      a0 += o0; a1 += o1;
    }
  }
  if (VARIANT == 1) {
    red[wave * 128 + lane]      = a0;
    red[wave * 128 + lane + 64] = a1;
    __syncthreads();
    if (wave == 0) {
      #pragma unroll
      for (int half = 0; half < 2; half++) {
        int e = lane + half * 64;
        partial[(size_t)blockIdx.x * E + e] =
            red[0 * 128 + e] + red[1 * 128 + e] + red[2 * 128 + e] + red[3 * 128 + e];
      }
    }
  }
}

// ---------------------------------------------------------------- generic fp32 GEMM (xproj only)
__global__ void gemm_bt(const float* __restrict__ A, int lda,
                        const float* __restrict__ B, int ldb,
                        float* __restrict__ C, int ldc,
                        int M, int N, int K) {
  __shared__ float As[16][68];
  __shared__ float Bs[16][68];
  int tx = threadIdx.x % 16, ty = threadIdx.x / 16;
  int rowBase = blockIdx.x * 64, colBase = blockIdx.y * 64;
  float acc[4][4] = {};
  int lr = threadIdx.x / 4;
  int lc = (threadIdx.x % 4) * 4;
  for (int k0 = 0; k0 < K; k0 += 16) {
    int ar = rowBase + lr;
    {
      float4 v = *(const float4*)&A[(size_t)ar * lda + k0 + lc];
      As[lc + 0][lr] = v.x; As[lc + 1][lr] = v.y;
      As[lc + 2][lr] = v.z; As[lc + 3][lr] = v.w;
    }
    int br = colBase + lr;
    if (br < N) {
      float4 v = *(const float4*)&B[(size_t)br * ldb + k0 + lc];
      Bs[lc + 0][lr] = v.x; Bs[lc + 1][lr] = v.y;
      Bs[lc + 2][lr] = v.z; Bs[lc + 3][lr] = v.w;
    } else {
      #pragma unroll
      for (int j = 0; j < 4; j++) Bs[lc + j][lr] = 0.f;
    }
    __syncthreads();
    #pragma unroll
    for (int kk = 0; kk < 16; kk++) {
      float4 a4 = *(const float4*)&As[kk][ty * 4];
      float4 b4 = *(const float4*)&Bs[kk][tx * 4];
      float a[4] = {a4.x, a4.y, a4.z, a4.w};
      float bv[4] = {b4.x, b4.y, b4.z, b4.w};
      #pragma unroll
      for (int i = 0; i < 4; i++)
        #pragma unroll
        for (int j = 0; j < 4; j++) acc[i][j] += a[i] * bv[j];
    }
    __syncthreads();
  }
  #pragma unroll
  for (int i = 0; i < 4; i++) {
    int r = rowBase + ty * 4 + i;
    #pragma unroll
    for (int j = 0; j < 4; j++) {
      int c = colBase + tx * 4 + j;
      if (c < N) C[(size_t)r * ldc + c] = acc[i][j];
    }
  }
}

// ---------------------------------------------------------------- causal depthwise conv + silu, 8 rows/thread
__global__ void conv_silu8(const float* __restrict__ uz, const float* __restrict__ cw,
                           const float* __restrict__ cb, float* __restrict__ uc) {
  int d = threadIdx.x;
  int r0 = blockIdx.x * 8;
  int b = r0 / L;
  int t0 = r0 % L;
  float w0 = cw[d * DCV + 0], w1 = cw[d * DCV + 1], w2 = cw[d * DCV + 2], w3 = cw[d * DCV + 3];
  float bias = cb[d];
  float uwin[11];
  #pragma unroll
  for (int j = 0; j < 11; j++) {
    int t = t0 + j - 3;
    uwin[j] = (t >= 0) ? uz[((size_t)b * L + t) * (2 * DI) + d] : 0.f;
  }
  #pragma unroll
  for (int j = 0; j < 8; j++) {
    float a = bias + w0 * uwin[j] + w1 * uwin[j + 1] + w2 * uwin[j + 2] + w3 * uwin[j + 3];
    uc[((size_t)r0 + j) * DI + d] = a / (1.f + __expf(-a));
  }
}

// ---------------------------------------------------------------- scan pass A (dtproj+softplus fused)
// hloc layout: [b][c][d][s]  (coalesced for threads=d); sumd: [b][c][d]
__global__ __launch_bounds__(256, 4)
void scan_passA(const float* __restrict__ uc, const float* __restrict__ xdbl,
                const float* __restrict__ dtw, const float* __restrict__ dtb,
                const float* __restrict__ A_log,
                float* __restrict__ hloc, float* __restrict__ sumd) {
  int b = blockIdx.x / NCH, c = blockIdx.x % NCH;
  int d = threadIdx.x;
  __shared__ float Bsh[CH][DS];
  __shared__ float Dsh[CH][DRR];
  {
    int i = threadIdx.x;
    int t0 = i >> 4, s = i & 15;
    size_t rb = ((size_t)b * L + c * CH + t0) * XDW;
    Bsh[t0][s] = xdbl[rb + DRR + s];
    if (i < CH * DRR) {
      int td = i >> 3, q = i & 7;
      Dsh[td][q] = xdbl[((size_t)b * L + c * CH + td) * XDW + q];
    }
  }
  // prefetch global while LDS staging is in flight
  float ut[CH];
  const float* uc_p = uc + ((size_t)b * L + c * CH) * DI + d;
  #pragma unroll
  for (int t0 = 0; t0 < CH; t0++) ut[t0] = uc_p[(size_t)t0 * DI];
  float Av[DS];
  #pragma unroll
  for (int s = 0; s < DS; s++) Av[s] = -__expf(A_log[d * DS + s]);
  float4 w0 = *(const float4*)(dtw + d * DRR);
  float4 w1 = *(const float4*)(dtw + d * DRR + 4);
  float bias = dtb[d];
  __syncthreads();
  float dl[CH];
  float sd = 0.f;
  #pragma unroll
  for (int t0 = 0; t0 < CH; t0++) {
    float4 D0 = *(const float4*)&Dsh[t0][0];
    float4 D1 = *(const float4*)&Dsh[t0][4];
    float v = bias + D0.x * w0.x + D0.y * w0.y + D0.z * w0.z + D0.w * w0.w
                   + D1.x * w1.x + D1.y * w1.y + D1.z * w1.z + D1.w * w1.w;
    dl[t0] = softplusf(v);
    sd += dl[t0];
  }
  float st[DS] = {};
  #pragma unroll
  for (int t0 = 0; t0 < CH; t0++) {
    float du = dl[t0] * ut[t0];
    float4 B0 = *(const float4*)&Bsh[t0][0];
    float4 B1 = *(const float4*)&Bsh[t0][4];
    float4 B2 = *(const float4*)&Bsh[t0][8];
    float4 B3 = *(const float4*)&Bsh[t0][12];
    float Bv[DS] = {B0.x, B0.y, B0.z, B0.w, B1.x, B1.y, B1.z, B1.w,
                    B2.x, B2.y, B2.z, B2.w, B3.x, B3.y, B3.z, B3.w};
    #pragma unroll
    for (int s = 0; s < DS; s++) {
      float a = __expf(dl[t0] * Av[s]);
      st[s] = a * st[s] + du * Bv[s];
    }
  }
  size_t base = (((size_t)b * NCH + c) * DI + d) * DS;
  *(float4*)&hloc[base + 0]  = float4{st[0], st[1], st[2], st[3]};
  *(float4*)&hloc[base + 4]  = float4{st[4], st[5], st[6], st[7]};
  *(float4*)&hloc[base + 8]  = float4{st[8], st[9], st[10], st[11]};
  *(float4*)&hloc[base + 12] = float4{st[12], st[13], st[14], st[15]};
  sumd[((size_t)b * NCH + c) * DI + d] = sd;
}

// ---------------------------------------------------------------- scan pass B: coalesced serial scan, depth-8 prefetch
#define PB_G 8
__global__ __launch_bounds__(64)
void scan_passB(const float* __restrict__ A_log, const float* __restrict__ hloc,
                const float* __restrict__ sumd, float* __restrict__ hinit) {
  int tid = threadIdx.x;
  int dgroup = blockIdx.x % (DI / 4);
  int b = blockIdx.x / (DI / 4);
  int d = dgroup * 4 + (tid >> 4);
  int s = tid & 15;
  float Av = -__expf(A_log[d * DS + s]);
  size_t off = (size_t)b * NCH * DI * DS + dgroup * 64 + tid;
  size_t soff = (size_t)b * NCH * DI + d;
  const size_t HST = (size_t)DI * DS;
  float bv[PB_G], sd[PB_G], bvn[PB_G], sdn[PB_G];
  #pragma unroll
  for (int j = 0; j < PB_G; j++) {
    bv[j] = hloc[off + j * HST];
    sd[j] = sumd[soff + j * DI];
  }
  float X = 0.f;
  for (int g = 0; g < NCH / PB_G; g++) {
    if (g + 1 < NCH / PB_G) {
      #pragma unroll
      for (int j = 0; j < PB_G; j++) {
        bvn[j] = hloc[off + (j + PB_G) * HST];
        sdn[j] = sumd[soff + (j + PB_G) * DI];
      }
    }
    #pragma unroll
    for (int j = 0; j < PB_G; j++) {
      float a = __expf(Av * sd[j]);
      hinit[off + j * HST] = X;
      X = a * X + bv[j];
    }
    #pragma unroll
    for (int j = 0; j < PB_G; j++) { bv[j] = bvn[j]; sd[j] = sdn[j]; }
    off += PB_G * HST;
    soff += PB_G * DI;
  }
}

// ---------------------------------------------------------------- scan pass C (dtproj fused; y -> bf16 hi/lo)
__global__ __launch_bounds__(256, 4)
void scan_passC(const float* __restrict__ uc, const float* __restrict__ xdbl,
                const float* __restrict__ dtw, const float* __restrict__ dtb,
                const float* __restrict__ A_log, const float* __restrict__ Dp,
                const float* __restrict__ uz, const float* __restrict__ hinit,
                u16* __restrict__ yhi, u16* __restrict__ ylo) {
  int b = blockIdx.x / NCH, c = blockIdx.x % NCH;
  int d = threadIdx.x;
  __shared__ float Bsh[CH][DS];
  __shared__ float Csh[CH][DS];
  __shared__ float Dsh[CH][DRR];
  {
    int i = threadIdx.x;
    int t0 = i >> 4, s = i & 15;
    size_t rb = ((size_t)b * L + c * CH + t0) * XDW;
    Bsh[t0][s] = xdbl[rb + DRR + s];
    Csh[t0][s] = xdbl[rb + DRR + DS + s];
    if (i < CH * DRR) {
      int td = i >> 3, q = i & 7;
      Dsh[td][q] = xdbl[((size_t)b * L + c * CH + td) * XDW + q];
    }
  }
  // prefetch
  float ut[CH];
  const float* uc_p = uc + ((size_t)b * L + c * CH) * DI + d;
  #pragma unroll
  for (int t0 = 0; t0 < CH; t0++) ut[t0] = uc_p[(size_t)t0 * DI];
  float st[DS];
  size_t hbase = (((size_t)b * NCH + c) * DI + d) * DS;
  {
    float4 h0 = *(const float4*)&hinit[hbase + 0];
    float4 h1 = *(const float4*)&hinit[hbase + 4];
    float4 h2 = *(const float4*)&hinit[hbase + 8];
    float4 h3 = *(const float4*)&hinit[hbase + 12];
    st[0]=h0.x; st[1]=h0.y; st[2]=h0.z; st[3]=h0.w;
    st[4]=h1.x; st[5]=h1.y; st[6]=h1.z; st[7]=h1.w;
    st[8]=h2.x; st[9]=h2.y; st[10]=h2.z; st[11]=h2.w;
    st[12]=h3.x; st[13]=h3.y; st[14]=h3.z; st[15]=h3.w;
  }
  float Av[DS];
  #pragma unroll
  for (int s = 0; s < DS; s++) Av[s] = -__expf(A_log[d * DS + s]);
  float4 w0 = *(const float4*)(dtw + d * DRR);
  float4 w1 = *(const float4*)(dtw + d * DRR + 4);
  float bias = dtb[d];
  float Dv = Dp[d];
  const float* z_p = uz + ((size_t)b * L + c * CH) * (2 * DI) + DI + d;
  size_t ybase = ((size_t)b * L + c * CH) * DI + d;
  __syncthreads();
  float dl[CH];
  #pragma unroll
  for (int t0 = 0; t0 < CH; t0++) {
    float4 D0 = *(const float4*)&Dsh[t0][0];
    float4 D1 = *(const float4*)&Dsh[t0][4];
    float v = bias + D0.x * w0.x + D0.y * w0.y + D0.z * w0.z + D0.w * w0.w
                   + D1.x * w1.x + D1.y * w1.y + D1.z * w1.z + D1.w * w1.w;
    dl[t0] = softplusf(v);
  }
  float znext = z_p[0];
  #pragma unroll
  for (int t0 = 0; t0 < CH; t0++) {
    float zz = znext;
    if (t0 < CH - 1) znext = z_p[(size_t)(t0 + 1) * (2 * DI)];
    float du = dl[t0] * ut[t0];
    float acc = Dv * ut[t0];
    float4 B0 = *(const float4*)&Bsh[t0][0];
    float4 B1 = *(const float4*)&Bsh[t0][4];
    float4 B2 = *(const float4*)&Bsh[t0][8];
    float4 B3 = *(const float4*)&Bsh[t0][12];
    float4 C0 = *(const float4*)&Csh[t0][0];
    float4 C1 = *(const float4*)&Csh[t0][4];
    float4 C2 = *(const float4*)&Csh[t0][8];
    float4 C3 = *(const float4*)&Csh[t0][12];
    float Bv[DS] = {B0.x, B0.y, B0.z, B0.w, B1.x, B1.y, B1.z, B1.w,
                    B2.x, B2.y, B2.z, B2.w, B3.x, B3.y, B3.z, B3.w};
    float Cv[DS] = {C0.x, C0.y, C0.z, C0.w, C1.x, C1.y, C1.z, C1.w,
                    C2.x, C2.y, C2.z, C2.w, C3.x, C3.y, C3.z, C3.w};
    #pragma unroll
    for (int s = 0; s < DS; s++) {
      float a = __expf(dl[t0] * Av[s]);
      st[s] = a * st[s] + du * Bv[s];
      acc += st[s] * Cv[s];
    }
    float v = acc * (zz / (1.f + __expf(-zz)));
    u16 hh = f2bf(v);
    yhi[ybase + (size_t)t0 * DI] = hh;
    ylo[ybase + (size_t)t0 * DI] = f2bf(v - bf2f(hh));
  }
}

// ---------------------------------------------------------------- final FC (reduce partials + project)
__global__ void fc_kernel(const float* __restrict__ partial, const float* __restrict__ fcw,
                          const float* __restrict__ fcb, float* __restrict__ out) {
  __shared__ float hm[BATCH * E];
  for (int idx = threadIdx.x; idx < BATCH * E; idx += 256) {
    int b = idx >> 7, e = idx & 127;
    float s = 0.f;
    for (int g2 = 0; g2 < 64; g2++) s += partial[(size_t)(b * 64 + g2) * E + e];
    hm[idx] = s;
  }
  __syncthreads();
  int i = threadIdx.x;
  if (i < BATCH * NC) {
    int b = i / NC, o = i % NC;
    float acc = 0.f;
    for (int e = 0; e < E; e++) acc += hm[b * E + e] * fcw[o * E + e];
    out[i] = acc * (1.f / L) + fcb[o];
  }
}

// ---------------------------------------------------------------- launch
extern "C" void kernel_launch(void* const* d_in, const int* in_sizes, int n_in,
                              void* d_out, int out_size, void* d_ws, size_t ws_size,
                              hipStream_t stream) {
  const float* x      = (const float*)d_in[0];
  const int*   oh     = (const int*)d_in[1];
  const int*   ot     = (const int*)d_in[2];
  const float* pe_w   = (const float*)d_in[3];
  const float* pe_b   = (const float*)d_in[4];
  const float* gamma  = (const float*)d_in[5];
  const float* beta   = (const float*)d_in[6];
  const float* ln_g   = (const float*)d_in[7];
  const float* ln_b   = (const float*)d_in[8];
  const float* inproj = (const float*)d_in[9];
  const float* conv_w = (const float*)d_in[10];
  const float* conv_b = (const float*)d_in[11];
  const float* xproj  = (const float*)d_in[12];
  const float* dtw    = (const float*)d_in[13];
  const float* dtb    = (const float*)d_in[14];
  const float* A_log  = (const float*)d_in[15];
  const float* Dp     = (const float*)d_in[16];
  const float* outw   = (const float*)d_in[17];
  const float* hn_g   = (const float*)d_in[18];
  const float* hn_b   = (const float*)d_in[19];
  const float* fc_w   = (const float*)d_in[20];
  const float* fc_b   = (const float*)d_in[21];
  float* out = (float*)d_out;

  char* ws = (char*)d_ws;
  size_t off = 0;
  auto alloc = [&](size_t bytes) { size_t o = off; off += (bytes + 255) & ~(size_t)255; return o; };
  float* h     = (float*)(ws + alloc((size_t)ROWS * E * 4));              // 8 MB
  u16*   xnhi  = (u16*)  (ws + alloc((size_t)ROWS * E * 2));              // 4 MB
  u16*   xnlo  = (u16*)  (ws + alloc((size_t)ROWS * E * 2));              // 4 MB
  float* uz    = (float*)(ws + alloc((size_t)ROWS * 2 * DI * 4));         // 32 MB
  float* uc    = (float*)(ws + alloc((size_t)ROWS * DI * 4));             // 16 MB
  float* xdbl  = (float*)(ws + alloc((size_t)ROWS * XDW * 4));            // 2.6 MB
  u16*   yhi   = (u16*)  (ws + alloc((size_t)ROWS * DI * 2));             // 8 MB
  u16*   ylo   = (u16*)  (ws + alloc((size_t)ROWS * DI * 2));             // 8 MB
  float* hloc  = (float*)(ws + alloc((size_t)BATCH * NCH * DI * DS * 4)); // 16.8 MB
  float* sumd  = (float*)(ws + alloc((size_t)BATCH * NCH * DI * 4));      // 1 MB
  u16*   wihi  = (u16*)  (ws + alloc((size_t)NBLK * 2 * DI * E * 2));     // 256 KB
  u16*   wilo  = (u16*)  (ws + alloc((size_t)NBLK * 2 * DI * E * 2));     // 256 KB
  u16*   wohi  = (u16*)  (ws + alloc((size_t)NBLK * E * DI * 2));         // 128 KB
  u16*   wolo  = (u16*)  (ws + alloc((size_t)NBLK * E * DI * 2));         // 128 KB
  float* partial = (float*)(ws + alloc((size_t)BATCH * 64 * E * 4));      // 128 KB
  float* hinit = hloc;    // passB: same-thread read-before-write per element

  embed_ln_split<<<ROWS / 4, 256, 0, stream>>>(x, oh, ot, pe_w, pe_b, gamma, beta,
                                               ln_g, ln_b, h, xnhi, xnlo);
  split_all<<<(NBLK * 2 * DI * E + NBLK * E * DI + 255) / 256, 256, 0, stream>>>(
      inproj, outw, wihi, wilo, wohi, wolo);

  for (int i = 0; i < NBLK; i++) {
    // uz = xn @ inproj^T   (M=ROWS, N=2*DI=512, K=E=128)
    dim3 g1(ROWS / 128, (2 * DI) / 128);
    mfma_gemm_lds<128, 0><<<g1, 256, 0, stream>>>(xnhi, xnlo,
                                                  wihi + (size_t)i * 2 * DI * E, wilo + (size_t)i * 2 * DI * E,
                                                  uz, ROWS, 2 * DI, E, 2 * DI);

    conv_silu8<<<ROWS / 8, 256, 0, stream>>>(uz, conv_w + i * DI * DCV, conv_b + i * DI, uc);

    dim3 g2(ROWS / 64, 1);
    gemm_bt<<<g2, 256, 0, stream>>>(uc, DI, xproj + (size_t)i * XDW * DI, DI,
                                    xdbl, XDW, ROWS, XDW, DI);

    scan_passA<<<BATCH * NCH, 256, 0, stream>>>(uc, xdbl, dtw + (size_t)i * DI * DRR, dtb + i * DI,
                                                A_log + (size_t)i * DI * DS, hloc, sumd);
    scan_passB<<<BATCH * (DI / 4), 64, 0, stream>>>(A_log + (size_t)i * DI * DS, hloc, sumd, hinit);
    scan_passC<<<BATCH * NCH, 256, 0, stream>>>(uc, xdbl, dtw + (size_t)i * DI * DRR, dtb + i * DI,
                                                A_log + (size_t)i * DI * DS, Dp + i * DI,
                                                uz, hinit, yhi, ylo);

    // outproj + residual + LN fused (grid 256 blocks; y read once)
    if (i == 0) {
      outproj_fused<0><<<ROWS / 64, 256, 0, stream>>>(yhi, ylo,
                                                      wohi + (size_t)i * E * DI, wolo + (size_t)i * E * DI,
                                                      h, ln_g + (i + 1) * E, ln_b + (i + 1) * E,
                                                      xnhi, xnlo, partial);
    } else {
      outproj_fused<1><<<ROWS / 64, 256, 0, stream>>>(yhi, ylo,
                                                      wohi + (size_t)i * E * DI, wolo + (size_t)i * E * DI,
                                                      h, hn_g, hn_b,
                                                      xnhi, xnlo, partial);
    }
  }

  fc_kernel<<<1, 256, 0, stream>>>(partial, fc_w, fc_b, out);
}